// Round 3
// baseline (636.503 us; speedup 1.0000x reference)
//
#include <hip/hip_runtime.h>

#define N_PTS 10000
#define NBATCH 2
#define COLS (N_PTS * NBATCH)

static __device__ __forceinline__ float leaky(float v) { return v > 0.f ? v : 0.2f * v; }

// ---------------- pack x0 = concat(coords, feats[:,:,3]) -> [4][COLS] ----------------
__global__ void pack_kernel(const float* __restrict__ coords, const float* __restrict__ feats,
                            float* __restrict__ X0) {
  int i = blockIdx.x * blockDim.x + threadIdx.x;
  if (i >= COLS) return;
  const float* cp = coords + (size_t)i * 3;
  X0[0 * COLS + i] = cp[0];
  X0[1 * COLS + i] = cp[1];
  X0[2 * COLS + i] = cp[2];
  X0[3 * COLS + i] = feats[(size_t)i * 4 + 3];
}

// ---------------- stacked EC weights: WS[0:O] = w_diff + w_ctr ; WS[O:2O] = w_diff --------
__global__ void prep_w(const float* __restrict__ ew, float* __restrict__ WS, int O, int C) {
  int i = blockIdx.x * blockDim.x + threadIdx.x;
  if (i >= O * C) return;
  int o = i / C, c = i - o * C;
  float wa = ew[(size_t)o * 2 * C + c];       // diff part
  float wb = ew[(size_t)o * 2 * C + C + c];   // ctr part
  WS[(size_t)o * C + c] = wa + wb;
  WS[(size_t)(O + o) * C + c] = wa;
}

// ---------------- fp32 GEMM: Out[M][COLS] = W[M][K] @ X[K][COLS] ----------------
// MODE 0: raw store. MODE 1: leaky(v*s+t). MODE 2: v*s+t, transposed store [b][n][Cf].
template <int K, int MODE>
__global__ __launch_bounds__(256) void gemm_kernel(
    const float* __restrict__ W, const float* __restrict__ X, float* __restrict__ Out,
    const float* __restrict__ s, const float* __restrict__ t, int Cf) {
  __shared__ float Ws[32][68];
  __shared__ float Xs[32][132];
  const int tid = threadIdx.x;
  const int col0 = blockIdx.x * 128;
  const int row0 = blockIdx.y * 64;
  const int tn = tid & 31, tm = tid >> 5;
  float acc[8][4];
#pragma unroll
  for (int i = 0; i < 8; i++)
#pragma unroll
    for (int j = 0; j < 4; j++) acc[i][j] = 0.f;

  const bool colok = (col0 + tn * 4) < COLS;

  for (int k0 = 0; k0 < K; k0 += 32) {
    {  // stage W tile (64 rows x 32 k), transposed into Ws[k][m]
      int m = tid >> 2;
      int kq = (tid & 3) * 8;
      if ((K & 31) == 0) {
        const float* wp = W + (size_t)(row0 + m) * K + k0 + kq;
        float4 w0 = *(const float4*)wp;
        float4 w1 = *(const float4*)(wp + 4);
        Ws[kq + 0][m] = w0.x; Ws[kq + 1][m] = w0.y; Ws[kq + 2][m] = w0.z; Ws[kq + 3][m] = w0.w;
        Ws[kq + 4][m] = w1.x; Ws[kq + 5][m] = w1.y; Ws[kq + 6][m] = w1.z; Ws[kq + 7][m] = w1.w;
      } else {  // K=4 path, guarded scalar
#pragma unroll
        for (int j = 0; j < 8; j++) {
          int k = kq + j;
          Ws[k][m] = (k0 + k < K) ? W[(size_t)(row0 + m) * K + k0 + k] : 0.f;
        }
      }
    }
// stage X tile (32 k x 128 cols)
#pragma unroll
    for (int p = 0; p < 4; p++) {
      int idx = tid + p * 256;
      int k = idx >> 5;
      int n4 = (idx & 31) << 2;
      int col = col0 + n4;
      float4 v = make_float4(0.f, 0.f, 0.f, 0.f);
      if (k0 + k < K && col < COLS) v = *(const float4*)(X + (size_t)(k0 + k) * COLS + col);
      *(float4*)&Xs[k][n4] = v;
    }
    __syncthreads();
#pragma unroll
    for (int k = 0; k < 32; k++) {
      float a[8], b[4];
      *(float4*)&a[0] = *(const float4*)&Ws[k][tm * 8];
      *(float4*)&a[4] = *(const float4*)&Ws[k][tm * 8 + 4];
      *(float4*)&b[0] = *(const float4*)&Xs[k][tn * 4];
#pragma unroll
      for (int i = 0; i < 8; i++)
#pragma unroll
        for (int j = 0; j < 4; j++) acc[i][j] = fmaf(a[i], b[j], acc[i][j]);
    }
    __syncthreads();
  }

  if (MODE == 0) {
    if (colok) {
#pragma unroll
      for (int i = 0; i < 8; i++) {
        int row = row0 + tm * 8 + i;
        float4 v = make_float4(acc[i][0], acc[i][1], acc[i][2], acc[i][3]);
        *(float4*)(Out + (size_t)row * COLS + col0 + tn * 4) = v;
      }
    }
  } else if (MODE == 1) {
    if (colok) {
#pragma unroll
      for (int i = 0; i < 8; i++) {
        int row = row0 + tm * 8 + i;
        float ss = s[row], tt = t[row];
        float4 v = make_float4(leaky(acc[i][0] * ss + tt), leaky(acc[i][1] * ss + tt),
                               leaky(acc[i][2] * ss + tt), leaky(acc[i][3] * ss + tt));
        *(float4*)(Out + (size_t)row * COLS + col0 + tn * 4) = v;
      }
    }
  } else {
    float sr[8], tr[8];
#pragma unroll
    for (int i = 0; i < 8; i++) {
      sr[i] = s[row0 + tm * 8 + i];
      tr[i] = t[row0 + tm * 8 + i];
    }
#pragma unroll
    for (int j = 0; j < 4; j++) {
      int col = col0 + tn * 4 + j;
      if (col < COLS) {
        int b = col / N_PTS, n = col - b * N_PTS;
        float* op = Out + ((size_t)b * N_PTS + n) * Cf + row0 + tm * 8;
        float4 v0 = make_float4(acc[0][j] * sr[0] + tr[0], acc[1][j] * sr[1] + tr[1],
                                acc[2][j] * sr[2] + tr[2], acc[3][j] * sr[3] + tr[3]);
        float4 v1 = make_float4(acc[4][j] * sr[4] + tr[4], acc[5][j] * sr[5] + tr[5],
                                acc[6][j] * sr[6] + tr[6], acc[7][j] * sr[7] + tr[7]);
        *(float4*)op = v0;
        *(float4*)(op + 4) = v1;
      }
    }
  }
}

// ---------------- edge finish: out = leaky((A - slidemin20(Bt, circular)) * s + t) --------
// AB rows [0:O) = A, [O:2O) = Bt. Window for output n starts at (N-n)%N.
__global__ __launch_bounds__(256) void edge_finish(const float* __restrict__ AB, int O,
                                                   const float* __restrict__ s,
                                                   const float* __restrict__ t,
                                                   float* __restrict__ Xout) {
  __shared__ float sh[1024 + 20];
  int o = blockIdx.y;
  int b = blockIdx.z;
  int n0 = blockIdx.x * 1024;
  int nb = min(1024, N_PTS - n0);
  const float* Bt = AB + (size_t)(O + o) * COLS + (size_t)b * N_PTS;
  int base = N_PTS - n0 - nb + 1;  // >= 1
  int L = nb + 19;
  for (int i = threadIdx.x; i < L; i += 256) {
    int p = base + i;
    if (p >= N_PTS) p -= N_PTS;
    sh[i] = Bt[p];
  }
  __syncthreads();
  const float* Arow = AB + (size_t)o * COLS + (size_t)b * N_PTS;
  float ss = s[o], tt = t[o];
  for (int d = threadIdx.x; d < nb; d += 256) {
    int w = nb - 1 - d;
    float mn = sh[w];
#pragma unroll
    for (int k = 1; k < 20; k++) mn = fminf(mn, sh[w + k]);
    float v = (Arow[n0 + d] - mn) * ss + tt;
    Xout[(size_t)o * COLS + (size_t)b * N_PTS + n0 + d] = leaky(v);
  }
}

// ---------------- fold sem head through Y5: SWp[20][512], biasp[20] ----------------
__global__ void sem_prep(const float* __restrict__ sem_w, const float* __restrict__ sem_b,
                         const float* __restrict__ fw3, const float* __restrict__ fs3,
                         const float* __restrict__ ft3, float* __restrict__ SWp,
                         float* __restrict__ biasp) {
  int i = blockIdx.x * blockDim.x + threadIdx.x;
  if (i < 20 * 512) {
    int cls = i / 512, k = i - cls * 512;
    float acc = 0.f;
    for (int c = 0; c < 256; c++) acc += sem_w[cls * 256 + c] * fs3[c] * fw3[(size_t)c * 512 + k];
    SWp[i] = acc;
  }
  if (i < 20) {
    float acc = sem_b[i];
    for (int c = 0; c < 256; c++) acc += sem_w[i * 256 + c] * ft3[c];
    biasp[i] = acc;
  }
}

__global__ __launch_bounds__(256) void sem_kernel(const float* __restrict__ Y5,
                                                  const float* __restrict__ SWp,
                                                  const float* __restrict__ biasp,
                                                  float* __restrict__ out) {
  __shared__ float w[20 * 512];
  __shared__ float bb[20];
  for (int i = threadIdx.x; i < 20 * 512; i += 256) w[i] = SWp[i];
  if (threadIdx.x < 20) bb[threadIdx.x] = biasp[threadIdx.x];
  __syncthreads();
  int col = blockIdx.x * 256 + threadIdx.x;
  if (col >= COLS) return;
  float acc[20];
#pragma unroll
  for (int c = 0; c < 20; c++) acc[c] = bb[c];
  for (int k = 0; k < 512; k++) {
    float x = Y5[(size_t)k * COLS + col];
#pragma unroll
    for (int c = 0; c < 20; c++) acc[c] = fmaf(x, w[c * 512 + k], acc[c]);
  }
  int b = col / N_PTS, n = col - b * N_PTS;
  float* op = out + ((size_t)b * N_PTS + n) * 20;
#pragma unroll
  for (int c = 0; c < 20; c++) op[c] = acc[c];
}

// ---------------- coords passthrough + zero masks ----------------
__global__ void misc_kernel(const float* __restrict__ coords, float* __restrict__ out_coords,
                            float* __restrict__ out_masks) {
  int i = blockIdx.x * blockDim.x + threadIdx.x;
  if (i < NBATCH * N_PTS * 3) out_coords[i] = coords[i];
  if (i < NBATCH * N_PTS) out_masks[i] = 0.f;
}

extern "C" void kernel_launch(void* const* d_in, const int* in_sizes, int n_in, void* d_out,
                              int out_size, void* d_ws, size_t ws_size, hipStream_t stream) {
  const float* coords = (const float*)d_in[0];
  const float* feats = (const float*)d_in[1];
  const float* ew1 = (const float*)d_in[2];
  const float* es1 = (const float*)d_in[3];
  const float* et1 = (const float*)d_in[4];
  const float* ew2 = (const float*)d_in[5];
  const float* es2 = (const float*)d_in[6];
  const float* et2 = (const float*)d_in[7];
  const float* ew3 = (const float*)d_in[8];
  const float* es3 = (const float*)d_in[9];
  const float* et3 = (const float*)d_in[10];
  const float* ew4 = (const float*)d_in[11];
  const float* es4 = (const float*)d_in[12];
  const float* et4 = (const float*)d_in[13];
  const float* w5 = (const float*)d_in[14];
  const float* s5 = (const float*)d_in[15];
  const float* t5 = (const float*)d_in[16];
  const float* fw1 = (const float*)d_in[17];
  const float* fs1 = (const float*)d_in[18];
  const float* ft1 = (const float*)d_in[19];
  const float* fw2 = (const float*)d_in[20];
  const float* fs2 = (const float*)d_in[21];
  const float* ft2 = (const float*)d_in[22];
  const float* fw3 = (const float*)d_in[23];
  const float* fs3 = (const float*)d_in[24];
  const float* ft3 = (const float*)d_in[25];
  const float* sem_w = (const float*)d_in[26];
  const float* sem_b = (const float*)d_in[27];
  float* out = (float*)d_out;
  float* ws = (float*)d_ws;

  // workspace layout (floats); total ~23.2M floats (~93 MB)
  float* X0 = ws;                   // 4   * 20000
  float* WS1 = ws + 80000;          // 128 * 4
  float* WS2 = ws + 80512;          // 128 * 64
  float* WS3 = ws + 88704;          // 256 * 64
  float* WS4 = ws + 105088;         // 256 * 128
  float* AB = ws + 140000;          // up to 256 * 20000 (shared A|Bt buffer)
  float* XC = ws + 5260000;         // 384 * 20000 (x1|x2|x3|x4 rows)
  float* Y5 = ws + 12940000;        // 512 * 20000
  float* SWp = ws + 23180000;       // 20 * 512
  float* Bp = ws + 23190240;        // 20

  // d_out layout (floats)
  float* out_f1 = out;              // 2*10000*128
  float* out_f2 = out + 2560000;    // 2*10000*128
  float* out_f3 = out + 5120000;    // 2*10000*256
  float* out_coords = out + 10240000;  // 60000
  float* out_masks = out + 10300000;   // 20000
  float* out_sem = out + 10320000;     // 2*10000*20

  dim3 blk(256);

  pack_kernel<<<dim3((COLS + 255) / 256), blk, 0, stream>>>(coords, feats, X0);
  prep_w<<<dim3((64 * 4 + 255) / 256), blk, 0, stream>>>(ew1, WS1, 64, 4);
  prep_w<<<dim3((64 * 64 + 255) / 256), blk, 0, stream>>>(ew2, WS2, 64, 64);
  prep_w<<<dim3((128 * 64 + 255) / 256), blk, 0, stream>>>(ew3, WS3, 128, 64);
  prep_w<<<dim3((128 * 128 + 255) / 256), blk, 0, stream>>>(ew4, WS4, 128, 128);

  const int GX = (COLS + 127) / 128;  // 157

  // EC1: K=4, A|Bt rows = 128
  gemm_kernel<4, 0><<<dim3(GX, 2), blk, 0, stream>>>(WS1, X0, AB, nullptr, nullptr, 0);
  edge_finish<<<dim3(10, 64, 2), blk, 0, stream>>>(AB, 64, es1, et1, XC);
  // EC2: K=64
  gemm_kernel<64, 0><<<dim3(GX, 2), blk, 0, stream>>>(WS2, XC, AB, nullptr, nullptr, 0);
  edge_finish<<<dim3(10, 64, 2), blk, 0, stream>>>(AB, 64, es2, et2, XC + (size_t)64 * COLS);
  // EC3: K=64 -> 128 out
  gemm_kernel<64, 0><<<dim3(GX, 4), blk, 0, stream>>>(WS3, XC + (size_t)64 * COLS, AB, nullptr,
                                                      nullptr, 0);
  edge_finish<<<dim3(10, 128, 2), blk, 0, stream>>>(AB, 128, es3, et3, XC + (size_t)128 * COLS);
  // EC4: K=128 -> 128 out
  gemm_kernel<128, 0><<<dim3(GX, 4), blk, 0, stream>>>(WS4, XC + (size_t)128 * COLS, AB, nullptr,
                                                       nullptr, 0);
  edge_finish<<<dim3(10, 128, 2), blk, 0, stream>>>(AB, 128, es4, et4, XC + (size_t)256 * COLS);

  // conv5: 384 -> 512, leaky
  gemm_kernel<384, 1><<<dim3(GX, 8), blk, 0, stream>>>(w5, XC, Y5, s5, t5, 0);

  // f-layers: 512 -> {128,128,256}, transposed store into d_out
  gemm_kernel<512, 2><<<dim3(GX, 2), blk, 0, stream>>>(fw1, Y5, out_f1, fs1, ft1, 128);
  gemm_kernel<512, 2><<<dim3(GX, 2), blk, 0, stream>>>(fw2, Y5, out_f2, fs2, ft2, 128);
  gemm_kernel<512, 2><<<dim3(GX, 4), blk, 0, stream>>>(fw3, Y5, out_f3, fs3, ft3, 256);

  // sem head folded through Y5
  sem_prep<<<dim3((20 * 512 + 255) / 256), blk, 0, stream>>>(sem_w, sem_b, fw3, fs3, ft3, SWp, Bp);
  sem_kernel<<<dim3((COLS + 255) / 256), blk, 0, stream>>>(Y5, SWp, Bp, out_sem);

  misc_kernel<<<dim3((60000 + 255) / 256), blk, 0, stream>>>(coords, out_coords, out_masks);
}

// Round 4
// 402.186 us; speedup vs baseline: 1.5826x; 1.5826x over previous
//
#include <hip/hip_runtime.h>

#define N_PTS 10000
#define NBATCH 2
#define COLS (N_PTS * NBATCH)
#define COLSP 20096  // padded to multiple of 128 for MFMA staging

typedef __attribute__((ext_vector_type(8))) short bf16x8;
typedef __attribute__((ext_vector_type(4))) float f32x4;

static __device__ __forceinline__ float leaky(float v) { return v > 0.f ? v : 0.2f * v; }

static __device__ __forceinline__ unsigned short f2b(float x) {
  unsigned int u = __float_as_uint(x);
  unsigned int r = (u + 0x7fffu + ((u >> 16) & 1u)) >> 16;
  return (unsigned short)r;
}
static __device__ __forceinline__ float b2f(unsigned short h) {
  return __uint_as_float((unsigned int)h << 16);
}

// ---------------- pack x0 = concat(coords, feats[:,:,3]) -> [4][COLS] ----------------
__global__ void pack_kernel(const float* __restrict__ coords, const float* __restrict__ feats,
                            float* __restrict__ X0) {
  int i = blockIdx.x * blockDim.x + threadIdx.x;
  if (i >= COLS) return;
  const float* cp = coords + (size_t)i * 3;
  X0[0 * COLS + i] = cp[0];
  X0[1 * COLS + i] = cp[1];
  X0[2 * COLS + i] = cp[2];
  X0[3 * COLS + i] = feats[(size_t)i * 4 + 3];
}

// ---------------- stacked EC weights: WS[0:O] = w_diff + w_ctr ; WS[O:2O] = w_diff --------
__global__ void prep_w(const float* __restrict__ ew, float* __restrict__ WS, int O, int C) {
  int i = blockIdx.x * blockDim.x + threadIdx.x;
  if (i >= O * C) return;
  int o = i / C, c = i - o * C;
  float wa = ew[(size_t)o * 2 * C + c];
  float wb = ew[(size_t)o * 2 * C + C + c];
  WS[(size_t)o * C + c] = wa + wb;
  WS[(size_t)(O + o) * C + c] = wa;
}

// ---------------- fp32 GEMM (EC layers only): Out[M][COLS] = W[M][K] @ X[K][COLS] --------
template <int K, int MODE>
__global__ __launch_bounds__(256) void gemm_kernel(
    const float* __restrict__ W, const float* __restrict__ X, float* __restrict__ Out,
    const float* __restrict__ s, const float* __restrict__ t, int Cf) {
  __shared__ float Ws[32][68];
  __shared__ float Xs[32][132];
  const int tid = threadIdx.x;
  const int col0 = blockIdx.x * 128;
  const int row0 = blockIdx.y * 64;
  const int tn = tid & 31, tm = tid >> 5;
  float acc[8][4];
#pragma unroll
  for (int i = 0; i < 8; i++)
#pragma unroll
    for (int j = 0; j < 4; j++) acc[i][j] = 0.f;

  const bool colok = (col0 + tn * 4) < COLS;

  for (int k0 = 0; k0 < K; k0 += 32) {
    {
      int m = tid >> 2;
      int kq = (tid & 3) * 8;
      if ((K & 31) == 0) {
        const float* wp = W + (size_t)(row0 + m) * K + k0 + kq;
        float4 w0 = *(const float4*)wp;
        float4 w1 = *(const float4*)(wp + 4);
        Ws[kq + 0][m] = w0.x; Ws[kq + 1][m] = w0.y; Ws[kq + 2][m] = w0.z; Ws[kq + 3][m] = w0.w;
        Ws[kq + 4][m] = w1.x; Ws[kq + 5][m] = w1.y; Ws[kq + 6][m] = w1.z; Ws[kq + 7][m] = w1.w;
      } else {
#pragma unroll
        for (int j = 0; j < 8; j++) {
          int k = kq + j;
          Ws[k][m] = (k0 + k < K) ? W[(size_t)(row0 + m) * K + k0 + k] : 0.f;
        }
      }
    }
#pragma unroll
    for (int p = 0; p < 4; p++) {
      int idx = tid + p * 256;
      int k = idx >> 5;
      int n4 = (idx & 31) << 2;
      int col = col0 + n4;
      float4 v = make_float4(0.f, 0.f, 0.f, 0.f);
      if (k0 + k < K && col < COLS) v = *(const float4*)(X + (size_t)(k0 + k) * COLS + col);
      *(float4*)&Xs[k][n4] = v;
    }
    __syncthreads();
#pragma unroll
    for (int k = 0; k < 32; k++) {
      float a[8], b[4];
      *(float4*)&a[0] = *(const float4*)&Ws[k][tm * 8];
      *(float4*)&a[4] = *(const float4*)&Ws[k][tm * 8 + 4];
      *(float4*)&b[0] = *(const float4*)&Xs[k][tn * 4];
#pragma unroll
      for (int i = 0; i < 8; i++)
#pragma unroll
        for (int j = 0; j < 4; j++) acc[i][j] = fmaf(a[i], b[j], acc[i][j]);
    }
    __syncthreads();
  }

  if (colok) {
#pragma unroll
    for (int i = 0; i < 8; i++) {
      int row = row0 + tm * 8 + i;
      float4 v = make_float4(acc[i][0], acc[i][1], acc[i][2], acc[i][3]);
      *(float4*)(Out + (size_t)row * COLS + col0 + tn * 4) = v;
    }
  }
}

// ---------------- edge finish: out = leaky((A - slidemin20(Bt, circular)) * s + t) --------
__global__ __launch_bounds__(256) void edge_finish(const float* __restrict__ AB, int O,
                                                   const float* __restrict__ s,
                                                   const float* __restrict__ t,
                                                   float* __restrict__ Xout) {
  __shared__ float sh[1024 + 20];
  int o = blockIdx.y;
  int b = blockIdx.z;
  int n0 = blockIdx.x * 1024;
  int nb = min(1024, N_PTS - n0);
  const float* Bt = AB + (size_t)(O + o) * COLS + (size_t)b * N_PTS;
  int base = N_PTS - n0 - nb + 1;
  int L = nb + 19;
  for (int i = threadIdx.x; i < L; i += 256) {
    int p = base + i;
    if (p >= N_PTS) p -= N_PTS;
    sh[i] = Bt[p];
  }
  __syncthreads();
  const float* Arow = AB + (size_t)o * COLS + (size_t)b * N_PTS;
  float ss = s[o], tt = t[o];
  for (int d = threadIdx.x; d < nb; d += 256) {
    int w = nb - 1 - d;
    float mn = sh[w];
#pragma unroll
    for (int k = 1; k < 20; k++) mn = fminf(mn, sh[w + k]);
    float v = (Arow[n0 + d] - mn) * ss + tt;
    Xout[(size_t)o * COLS + (size_t)b * N_PTS + n0 + d] = leaky(v);
  }
}

// ---------------- fold sem head through Y5: SWp[20][512], biasp[20] ----------------
__global__ void sem_prep(const float* __restrict__ sem_w, const float* __restrict__ sem_b,
                         const float* __restrict__ fw3, const float* __restrict__ fs3,
                         const float* __restrict__ ft3, float* __restrict__ SWp,
                         float* __restrict__ biasp) {
  int i = blockIdx.x * blockDim.x + threadIdx.x;
  if (i < 20 * 512) {
    int cls = i / 512, k = i - cls * 512;
    float acc = 0.f;
    for (int c = 0; c < 256; c++) acc += sem_w[cls * 256 + c] * fs3[c] * fw3[(size_t)c * 512 + k];
    SWp[i] = acc;
  }
  if (i < 20) {
    float acc = sem_b[i];
    for (int c = 0; c < 256; c++) acc += sem_w[i * 256 + c] * ft3[c];
    biasp[i] = acc;
  }
}

// ------------- split conv5 weights: Wc[512][1152] = [hi | hi | lo] of w5[512][384] -------
__global__ void split_w5(const float* __restrict__ w5, unsigned short* __restrict__ Wc) {
  int i = blockIdx.x * 256 + threadIdx.x;
  if (i >= 512 * 384) return;
  int m = i / 384, k = i - m * 384;
  float w = w5[i];
  unsigned short hi = f2b(w);
  unsigned short lo = f2b(w - b2f(hi));
  unsigned short* row = Wc + (size_t)m * 1152;
  row[k] = hi;
  row[384 + k] = hi;
  row[768 + k] = lo;
}

// ------------- split fused-f weights: Wc[640][1536]; rows: fw1|fw2|fw3|SWp|zeros ---------
__global__ void split_wf(const float* __restrict__ fw1, const float* __restrict__ fw2,
                         const float* __restrict__ fw3, const float* __restrict__ SWp,
                         const float* __restrict__ fs1, const float* __restrict__ ft1,
                         const float* __restrict__ fs2, const float* __restrict__ ft2,
                         const float* __restrict__ fs3, const float* __restrict__ ft3,
                         const float* __restrict__ Bp, unsigned short* __restrict__ Wc,
                         float* __restrict__ sF, float* __restrict__ tF) {
  int i = blockIdx.x * 256 + threadIdx.x;
  if (i >= 640 * 512) return;
  int m = i >> 9, k = i & 511;
  float w = 0.f, sv = 0.f, tv = 0.f;
  if (m < 128) {
    w = fw1[(size_t)m * 512 + k]; sv = fs1[m]; tv = ft1[m];
  } else if (m < 256) {
    w = fw2[(size_t)(m - 128) * 512 + k]; sv = fs2[m - 128]; tv = ft2[m - 128];
  } else if (m < 512) {
    w = fw3[(size_t)(m - 256) * 512 + k]; sv = fs3[m - 256]; tv = ft3[m - 256];
  } else if (m < 532) {
    w = SWp[(size_t)(m - 512) * 512 + k]; sv = 1.f; tv = Bp[m - 512];
  }
  unsigned short hi = f2b(w);
  unsigned short lo = f2b(w - b2f(hi));
  unsigned short* row = Wc + (size_t)m * 1536;
  row[k] = hi;
  row[512 + k] = hi;
  row[1024 + k] = lo;
  if (k == 0) { sF[m] = sv; tF[m] = tv; }
}

// ------------- transpose+split XC[384][COLS] fp32 -> XCt[n][768] bf16 (hi|lo) ------------
__global__ __launch_bounds__(256) void xpose_split(const float* __restrict__ XC,
                                                   unsigned short* __restrict__ XCt) {
  __shared__ float tile[32][65];
  int n0 = blockIdx.x * 64;
  int c0 = blockIdx.y * 32;
#pragma unroll
  for (int i = 0; i < 8; i++) {
    int e = threadIdx.x + i * 256;
    int c = e >> 6, n = e & 63;
    float v = 0.f;
    if (n0 + n < COLS) v = XC[(size_t)(c0 + c) * COLS + n0 + n];
    tile[c][n] = v;
  }
  __syncthreads();
#pragma unroll
  for (int i = 0; i < 2; i++) {
    int e = threadIdx.x + i * 256;
    int n = e >> 3, cq = (e & 7) * 4;
    if (n0 + n >= COLS) continue;
    unsigned short h[4], l[4];
#pragma unroll
    for (int j = 0; j < 4; j++) {
      float v = tile[cq + j][n];
      h[j] = f2b(v);
      l[j] = f2b(v - b2f(h[j]));
    }
    unsigned short* op = XCt + (size_t)(n0 + n) * 768 + c0 + cq;
    *(ushort4*)op = make_ushort4(h[0], h[1], h[2], h[3]);
    *(ushort4*)(op + 384) = make_ushort4(l[0], l[1], l[2], l[3]);
  }
}

// ---------------- MFMA GEMM: Out[M][n] = Wc[M][KP] @ Xsplit, both k-contiguous ----------
// Xt is point-major [COLSP][XSTR] bf16: cols [0,KX)=hi, [KX,2KX)=lo; k' in [2KX,3KX) re-reads hi.
// MODE 0: conv5 -> Y5t[n][1024] bf16 hi|lo, val=leaky(v*s+t).
// MODE 1: fused f1/f2/f3/sem fp32 stores, val=v*s+t, row ranges 0/128/256/512..532.
template <int KP, int KX, int XSTR, int MODE>
__global__ __launch_bounds__(256) void mgemm(
    const unsigned short* __restrict__ Wc, const unsigned short* __restrict__ Xt,
    float* __restrict__ O0, float* __restrict__ O1, float* __restrict__ O2,
    float* __restrict__ O3, unsigned short* __restrict__ Yt, const float* __restrict__ s,
    const float* __restrict__ t) {
  __shared__ unsigned short Al[128 * 32];
  __shared__ unsigned short Bl[128 * 32];
  const int tid = threadIdx.x;
  const int wid = tid >> 6, lane = tid & 63;
  const int col0 = blockIdx.x * 128;
  const int row0 = blockIdx.y * 128;
  const int wm = wid >> 1, wn = wid & 1;  // 2x2 waves, each 64x64
  f32x4 acc[4][4];
  f32x4 z = {0.f, 0.f, 0.f, 0.f};
#pragma unroll
  for (int i = 0; i < 4; i++)
#pragma unroll
    for (int j = 0; j < 4; j++) acc[i][j] = z;

  for (int k0 = 0; k0 < KP; k0 += 32) {
    int xoff = (k0 < 2 * KX) ? k0 : k0 - 2 * KX;
#pragma unroll
    for (int p = 0; p < 2; p++) {
      int idx = tid + p * 256;            // 0..511, 16B chunks
      int r = idx >> 2, kq = (idx & 3) * 8;
      __builtin_amdgcn_global_load_lds(
          (const __attribute__((address_space(1))) unsigned int*)(Wc +
                                                                  (size_t)(row0 + r) * KP + k0 + kq),
          (__attribute__((address_space(3))) unsigned int*)(Al + idx * 8), 16, 0, 0);
      __builtin_amdgcn_global_load_lds(
          (const __attribute__((address_space(1))) unsigned int*)(Xt +
                                                                  (size_t)(col0 + r) * XSTR + xoff + kq),
          (__attribute__((address_space(3))) unsigned int*)(Bl + idx * 8), 16, 0, 0);
    }
    __syncthreads();
    bf16x8 a[4], b[4];
#pragma unroll
    for (int f = 0; f < 4; f++) {
      int m = wm * 64 + f * 16 + (lane & 15);
      a[f] = *(const bf16x8*)(Al + m * 32 + (lane >> 4) * 8);
      int n = wn * 64 + f * 16 + (lane & 15);
      b[f] = *(const bf16x8*)(Bl + n * 32 + (lane >> 4) * 8);
    }
#pragma unroll
    for (int i = 0; i < 4; i++)
#pragma unroll
      for (int j = 0; j < 4; j++)
        acc[i][j] = __builtin_amdgcn_mfma_f32_16x16x32_bf16(a[i], b[j], acc[i][j], 0, 0, 0);
    __syncthreads();
  }

  // epilogue: lane holds D[4*(lane>>4)+r][lane&15] per 16x16 frag
#pragma unroll
  for (int j = 0; j < 4; j++) {
    int n = col0 + wn * 64 + j * 16 + (lane & 15);
    if (n >= COLS) continue;
#pragma unroll
    for (int i = 0; i < 4; i++) {
      int mb = row0 + wm * 64 + i * 16 + 4 * (lane >> 4);
      if (MODE == 0) {
        float vr[4];
        unsigned short h[4], l[4];
#pragma unroll
        for (int r = 0; r < 4; r++) {
          float v = acc[i][j][r] * s[mb + r] + t[mb + r];
          v = leaky(v);
          h[r] = f2b(v);
          l[r] = f2b(v - b2f(h[r]));
          vr[r] = v;
        }
        (void)vr;
        unsigned short* yp = Yt + (size_t)n * 1024 + mb;
        *(ushort4*)yp = make_ushort4(h[0], h[1], h[2], h[3]);
        *(ushort4*)(yp + 512) = make_ushort4(l[0], l[1], l[2], l[3]);
      } else {
        float4 v;
        v.x = acc[i][j][0] * s[mb + 0] + t[mb + 0];
        v.y = acc[i][j][1] * s[mb + 1] + t[mb + 1];
        v.z = acc[i][j][2] * s[mb + 2] + t[mb + 2];
        v.w = acc[i][j][3] * s[mb + 3] + t[mb + 3];
        float* p;
        if (mb < 128)
          p = O0 + (size_t)n * 128 + mb;
        else if (mb < 256)
          p = O1 + (size_t)n * 128 + (mb - 128);
        else if (mb < 512)
          p = O2 + (size_t)n * 256 + (mb - 256);
        else if (mb < 532)
          p = O3 + (size_t)n * 20 + (mb - 512);
        else
          continue;
        *(float4*)p = v;
      }
    }
  }
}

// ---------------- coords passthrough + zero masks ----------------
__global__ void misc_kernel(const float* __restrict__ coords, float* __restrict__ out_coords,
                            float* __restrict__ out_masks) {
  int i = blockIdx.x * blockDim.x + threadIdx.x;
  if (i < NBATCH * N_PTS * 3) out_coords[i] = coords[i];
  if (i < NBATCH * N_PTS) out_masks[i] = 0.f;
}

extern "C" void kernel_launch(void* const* d_in, const int* in_sizes, int n_in, void* d_out,
                              int out_size, void* d_ws, size_t ws_size, hipStream_t stream) {
  const float* coords = (const float*)d_in[0];
  const float* feats = (const float*)d_in[1];
  const float* ew1 = (const float*)d_in[2];
  const float* es1 = (const float*)d_in[3];
  const float* et1 = (const float*)d_in[4];
  const float* ew2 = (const float*)d_in[5];
  const float* es2 = (const float*)d_in[6];
  const float* et2 = (const float*)d_in[7];
  const float* ew3 = (const float*)d_in[8];
  const float* es3 = (const float*)d_in[9];
  const float* et3 = (const float*)d_in[10];
  const float* ew4 = (const float*)d_in[11];
  const float* es4 = (const float*)d_in[12];
  const float* et4 = (const float*)d_in[13];
  const float* w5 = (const float*)d_in[14];
  const float* s5 = (const float*)d_in[15];
  const float* t5 = (const float*)d_in[16];
  const float* fw1 = (const float*)d_in[17];
  const float* fs1 = (const float*)d_in[18];
  const float* ft1 = (const float*)d_in[19];
  const float* fw2 = (const float*)d_in[20];
  const float* fs2 = (const float*)d_in[21];
  const float* ft2 = (const float*)d_in[22];
  const float* fw3 = (const float*)d_in[23];
  const float* fs3 = (const float*)d_in[24];
  const float* ft3 = (const float*)d_in[25];
  const float* sem_w = (const float*)d_in[26];
  const float* sem_b = (const float*)d_in[27];
  float* out = (float*)d_out;
  float* ws = (float*)d_ws;

  // workspace layout (float offsets; total 21,452,736 f = 85.8 MB)
  float* X0 = ws;                                    // 80000
  float* WS1 = ws + 80000;                           // 512
  float* WS2 = ws + 80512;                           // 8192
  float* WS3 = ws + 88704;                           // 16384
  float* WS4 = ws + 105088;                          // 32768
  float* sF = ws + 137856;                           // 640
  float* tF = ws + 138496;                           // 640
  float* SWp = ws + 139136;                          // 10240
  float* Bp = ws + 149376;                           // 64
  unsigned short* Wc5 = (unsigned short*)(ws + 149440);   // 512*1152 ush
  unsigned short* WcF = (unsigned short*)(ws + 444352);   // 640*1536 ush
  unsigned short* XCt = (unsigned short*)(ws + 935872);   // 20096*768 ush
  float* AB = ws + 8652736;                          // 256*20000 f
  float* XC = ws + 13772736;                         // 384*20000 f
  // Y5t aliases AB..XC region (both dead after xpose_split): 20096*1024 ush
  unsigned short* Y5t = (unsigned short*)(ws + 8652736);

  // d_out layout (floats)
  float* out_f1 = out;                 // 2*10000*128
  float* out_f2 = out + 2560000;       // 2*10000*128
  float* out_f3 = out + 5120000;       // 2*10000*256
  float* out_coords = out + 10240000;  // 60000
  float* out_masks = out + 10300000;   // 20000
  float* out_sem = out + 10320000;     // 2*10000*20

  dim3 blk(256);
  const int GX = (COLS + 127) / 128;  // 157

  pack_kernel<<<dim3((COLS + 255) / 256), blk, 0, stream>>>(coords, feats, X0);
  prep_w<<<dim3(1), blk, 0, stream>>>(ew1, WS1, 64, 4);
  prep_w<<<dim3(16), blk, 0, stream>>>(ew2, WS2, 64, 64);
  prep_w<<<dim3(32), blk, 0, stream>>>(ew3, WS3, 128, 64);
  prep_w<<<dim3(64), blk, 0, stream>>>(ew4, WS4, 128, 128);

  // EC chain (fp32, proven)
  gemm_kernel<4, 0><<<dim3(GX, 2), blk, 0, stream>>>(WS1, X0, AB, nullptr, nullptr, 0);
  edge_finish<<<dim3(10, 64, 2), blk, 0, stream>>>(AB, 64, es1, et1, XC);
  gemm_kernel<64, 0><<<dim3(GX, 2), blk, 0, stream>>>(WS2, XC, AB, nullptr, nullptr, 0);
  edge_finish<<<dim3(10, 64, 2), blk, 0, stream>>>(AB, 64, es2, et2, XC + (size_t)64 * COLS);
  gemm_kernel<64, 0><<<dim3(GX, 4), blk, 0, stream>>>(WS3, XC + (size_t)64 * COLS, AB, nullptr,
                                                      nullptr, 0);
  edge_finish<<<dim3(10, 128, 2), blk, 0, stream>>>(AB, 128, es3, et3, XC + (size_t)128 * COLS);
  gemm_kernel<128, 0><<<dim3(GX, 4), blk, 0, stream>>>(WS4, XC + (size_t)128 * COLS, AB, nullptr,
                                                       nullptr, 0);
  edge_finish<<<dim3(10, 128, 2), blk, 0, stream>>>(AB, 128, es4, et4, XC + (size_t)256 * COLS);

  // weight prep for MFMA path
  split_w5<<<dim3(768), blk, 0, stream>>>(w5, Wc5);
  sem_prep<<<dim3(40), blk, 0, stream>>>(sem_w, sem_b, fw3, fs3, ft3, SWp, Bp);
  split_wf<<<dim3(1280), blk, 0, stream>>>(fw1, fw2, fw3, SWp, fs1, ft1, fs2, ft2, fs3, ft3, Bp,
                                           WcF, sF, tF);

  // activations: XC -> point-major bf16 hi/lo
  xpose_split<<<dim3(313, 12), blk, 0, stream>>>(XC, XCt);

  // conv5: [512][1152] @ XCt -> Y5t (leaky, split bf16)  -- overwrites AB/XC region
  mgemm<1152, 384, 768, 0><<<dim3(GX, 4), blk, 0, stream>>>(Wc5, XCt, nullptr, nullptr, nullptr,
                                                            nullptr, Y5t, s5, t5);

  // fused f1|f2|f3|sem: [640][1536] @ Y5t -> d_out
  mgemm<1536, 512, 1024, 1><<<dim3(GX, 5), blk, 0, stream>>>(WcF, Y5t, out_f1, out_f2, out_f3,
                                                             out_sem, nullptr, sF, tF);

  misc_kernel<<<dim3(236), blk, 0, stream>>>(coords, out_coords, out_masks);
}

// Round 7
// 397.391 us; speedup vs baseline: 1.6017x; 1.0121x over previous
//
#include <hip/hip_runtime.h>

#define N_PTS 10000
#define NBATCH 2
#define COLS (N_PTS * NBATCH)
#define COLSP 20096  // padded to multiple of 128 for MFMA staging

typedef __attribute__((ext_vector_type(8))) short bf16x8;
typedef __attribute__((ext_vector_type(4))) float f32x4;

static __device__ __forceinline__ float leaky(float v) { return v > 0.f ? v : 0.2f * v; }

static __device__ __forceinline__ unsigned short f2b(float x) {
  unsigned int u = __float_as_uint(x);
  unsigned int r = (u + 0x7fffu + ((u >> 16) & 1u)) >> 16;
  return (unsigned short)r;
}
static __device__ __forceinline__ float b2f(unsigned short h) {
  return __uint_as_float((unsigned int)h << 16);
}

// ---------------- fused prep: pack X0 + all 4 EC weight folds ----------------
static __device__ __forceinline__ void prep_one(const float* __restrict__ ew,
                                                float* __restrict__ WS, int O, int C, int i) {
  int o = i / C, c = i - o * C;
  float wa = ew[(size_t)o * 2 * C + c];
  float wb = ew[(size_t)o * 2 * C + C + c];
  WS[(size_t)o * C + c] = wa + wb;
  WS[(size_t)(O + o) * C + c] = wa;
}

__global__ void prep_all(const float* __restrict__ coords, const float* __restrict__ feats,
                         float* __restrict__ X0, const float* __restrict__ ew1,
                         float* __restrict__ WS1, const float* __restrict__ ew2,
                         float* __restrict__ WS2, const float* __restrict__ ew3,
                         float* __restrict__ WS3, const float* __restrict__ ew4,
                         float* __restrict__ WS4) {
  int i = blockIdx.x * 256 + threadIdx.x;
  if (i < COLS) {
    const float* cp = coords + (size_t)i * 3;
    X0[0 * COLS + i] = cp[0];
    X0[1 * COLS + i] = cp[1];
    X0[2 * COLS + i] = cp[2];
    X0[3 * COLS + i] = feats[(size_t)i * 4 + 3];
    return;
  }
  i -= COLS;
  if (i < 256) { prep_one(ew1, WS1, 64, 4, i); return; }
  i -= 256;
  if (i < 4096) { prep_one(ew2, WS2, 64, 64, i); return; }
  i -= 4096;
  if (i < 8192) { prep_one(ew3, WS3, 128, 64, i); return; }
  i -= 8192;
  if (i < 16384) { prep_one(ew4, WS4, 128, 128, i); return; }
}

// ---------------- fp32 GEMM (EC layers only): Out[M][COLS] = W[M][K] @ X[K][COLS] --------
template <int K, int MODE>
__global__ __launch_bounds__(256) void gemm_kernel(
    const float* __restrict__ W, const float* __restrict__ X, float* __restrict__ Out,
    const float* __restrict__ s, const float* __restrict__ t, int Cf) {
  __shared__ float Ws[32][68];
  __shared__ float Xs[32][132];
  const int tid = threadIdx.x;
  const int col0 = blockIdx.x * 128;
  const int row0 = blockIdx.y * 64;
  const int tn = tid & 31, tm = tid >> 5;
  float acc[8][4];
#pragma unroll
  for (int i = 0; i < 8; i++)
#pragma unroll
    for (int j = 0; j < 4; j++) acc[i][j] = 0.f;

  const bool colok = (col0 + tn * 4) < COLS;

  for (int k0 = 0; k0 < K; k0 += 32) {
    {
      int m = tid >> 2;
      int kq = (tid & 3) * 8;
      if ((K & 31) == 0) {
        const float* wp = W + (size_t)(row0 + m) * K + k0 + kq;
        float4 w0 = *(const float4*)wp;
        float4 w1 = *(const float4*)(wp + 4);
        Ws[kq + 0][m] = w0.x; Ws[kq + 1][m] = w0.y; Ws[kq + 2][m] = w0.z; Ws[kq + 3][m] = w0.w;
        Ws[kq + 4][m] = w1.x; Ws[kq + 5][m] = w1.y; Ws[kq + 6][m] = w1.z; Ws[kq + 7][m] = w1.w;
      } else {
#pragma unroll
        for (int j = 0; j < 8; j++) {
          int k = kq + j;
          Ws[k][m] = (k0 + k < K) ? W[(size_t)(row0 + m) * K + k0 + k] : 0.f;
        }
      }
    }
#pragma unroll
    for (int p = 0; p < 4; p++) {
      int idx = tid + p * 256;
      int k = idx >> 5;
      int n4 = (idx & 31) << 2;
      int col = col0 + n4;
      float4 v = make_float4(0.f, 0.f, 0.f, 0.f);
      if (k0 + k < K && col < COLS) v = *(const float4*)(X + (size_t)(k0 + k) * COLS + col);
      *(float4*)&Xs[k][n4] = v;
    }
    __syncthreads();
#pragma unroll
    for (int k = 0; k < 32; k++) {
      float a[8], b[4];
      *(float4*)&a[0] = *(const float4*)&Ws[k][tm * 8];
      *(float4*)&a[4] = *(const float4*)&Ws[k][tm * 8 + 4];
      *(float4*)&b[0] = *(const float4*)&Xs[k][tn * 4];
#pragma unroll
      for (int i = 0; i < 8; i++)
#pragma unroll
        for (int j = 0; j < 4; j++) acc[i][j] = fmaf(a[i], b[j], acc[i][j]);
    }
    __syncthreads();
  }

  if (colok) {
#pragma unroll
    for (int i = 0; i < 8; i++) {
      int row = row0 + tm * 8 + i;
      float4 v = make_float4(acc[i][0], acc[i][1], acc[i][2], acc[i][3]);
      *(float4*)(Out + (size_t)row * COLS + col0 + tn * 4) = v;
    }
  }
}

// ---------------- edge finish: out = leaky((A - slidemin20(Bt, circular)) * s + t) --------
__global__ __launch_bounds__(256) void edge_finish(const float* __restrict__ AB, int O,
                                                   const float* __restrict__ s,
                                                   const float* __restrict__ t,
                                                   float* __restrict__ Xout) {
  __shared__ float sh[1024 + 20];
  int o = blockIdx.y;
  int b = blockIdx.z;
  int n0 = blockIdx.x * 1024;
  int nb = min(1024, N_PTS - n0);
  const float* Bt = AB + (size_t)(O + o) * COLS + (size_t)b * N_PTS;
  int base = N_PTS - n0 - nb + 1;
  int L = nb + 19;
  for (int i = threadIdx.x; i < L; i += 256) {
    int p = base + i;
    if (p >= N_PTS) p -= N_PTS;
    sh[i] = Bt[p];
  }
  __syncthreads();
  const float* Arow = AB + (size_t)o * COLS + (size_t)b * N_PTS;
  float ss = s[o], tt = t[o];
  for (int d = threadIdx.x; d < nb; d += 256) {
    int w = nb - 1 - d;
    float mn = sh[w];
#pragma unroll
    for (int k = 1; k < 20; k++) mn = fminf(mn, sh[w + k]);
    float v = (Arow[n0 + d] - mn) * ss + tt;
    Xout[(size_t)o * COLS + (size_t)b * N_PTS + n0 + d] = leaky(v);
  }
}

// ---------------- fold sem head through Y5: SWp[20][512], biasp[20] ----------------
__global__ void sem_prep(const float* __restrict__ sem_w, const float* __restrict__ sem_b,
                         const float* __restrict__ fw3, const float* __restrict__ fs3,
                         const float* __restrict__ ft3, float* __restrict__ SWp,
                         float* __restrict__ biasp) {
  int i = blockIdx.x * blockDim.x + threadIdx.x;
  if (i < 20 * 512) {
    int cls = i / 512, k = i - cls * 512;
    float acc = 0.f;
    for (int c = 0; c < 256; c++) acc += sem_w[cls * 256 + c] * fs3[c] * fw3[(size_t)c * 512 + k];
    SWp[i] = acc;
  }
  if (i < 20) {
    float acc = sem_b[i];
    for (int c = 0; c < 256; c++) acc += sem_w[i * 256 + c] * ft3[c];
    biasp[i] = acc;
  }
}

// ------------- split conv5 weights: Wc[512][1152] = [hi | hi | lo] of w5[512][384] -------
__global__ void split_w5(const float* __restrict__ w5, unsigned short* __restrict__ Wc) {
  int i = blockIdx.x * 256 + threadIdx.x;
  if (i >= 512 * 384) return;
  int m = i / 384, k = i - m * 384;
  float w = w5[i];
  unsigned short hi = f2b(w);
  unsigned short lo = f2b(w - b2f(hi));
  unsigned short* row = Wc + (size_t)m * 1152;
  row[k] = hi;
  row[384 + k] = hi;
  row[768 + k] = lo;
}

// ------------- split fused-f weights: Wc[640][1536]; rows: fw1|fw2|fw3|SWp|zeros ---------
__global__ void split_wf(const float* __restrict__ fw1, const float* __restrict__ fw2,
                         const float* __restrict__ fw3, const float* __restrict__ SWp,
                         const float* __restrict__ fs1, const float* __restrict__ ft1,
                         const float* __restrict__ fs2, const float* __restrict__ ft2,
                         const float* __restrict__ fs3, const float* __restrict__ ft3,
                         const float* __restrict__ Bp, unsigned short* __restrict__ Wc,
                         float* __restrict__ sF, float* __restrict__ tF) {
  int i = blockIdx.x * 256 + threadIdx.x;
  if (i >= 640 * 512) return;
  int m = i >> 9, k = i & 511;
  float w = 0.f, sv = 0.f, tv = 0.f;
  if (m < 128) {
    w = fw1[(size_t)m * 512 + k]; sv = fs1[m]; tv = ft1[m];
  } else if (m < 256) {
    w = fw2[(size_t)(m - 128) * 512 + k]; sv = fs2[m - 128]; tv = ft2[m - 128];
  } else if (m < 512) {
    w = fw3[(size_t)(m - 256) * 512 + k]; sv = fs3[m - 256]; tv = ft3[m - 256];
  } else if (m < 532) {
    w = SWp[(size_t)(m - 512) * 512 + k]; sv = 1.f; tv = Bp[m - 512];
  }
  unsigned short hi = f2b(w);
  unsigned short lo = f2b(w - b2f(hi));
  unsigned short* row = Wc + (size_t)m * 1536;
  row[k] = hi;
  row[512 + k] = hi;
  row[1024 + k] = lo;
  if (k == 0) { sF[m] = sv; tF[m] = tv; }
}

// ------------- transpose+split XC[384][COLS] fp32 -> XCt[n][768] bf16 (hi|lo) ------------
__global__ __launch_bounds__(256) void xpose_split(const float* __restrict__ XC,
                                                   unsigned short* __restrict__ XCt) {
  __shared__ float tile[32][65];
  int n0 = blockIdx.x * 64;
  int c0 = blockIdx.y * 32;
#pragma unroll
  for (int i = 0; i < 8; i++) {
    int e = threadIdx.x + i * 256;
    int c = e >> 6, n = e & 63;
    float v = 0.f;
    if (n0 + n < COLS) v = XC[(size_t)(c0 + c) * COLS + n0 + n];
    tile[c][n] = v;
  }
  __syncthreads();
#pragma unroll
  for (int i = 0; i < 2; i++) {
    int e = threadIdx.x + i * 256;
    int n = e >> 3, cq = (e & 7) * 4;
    if (n0 + n >= COLS) continue;
    unsigned short h[4], l[4];
#pragma unroll
    for (int j = 0; j < 4; j++) {
      float v = tile[cq + j][n];
      h[j] = f2b(v);
      l[j] = f2b(v - b2f(h[j]));
    }
    unsigned short* op = XCt + (size_t)(n0 + n) * 768 + c0 + cq;
    *(ushort4*)op = make_ushort4(h[0], h[1], h[2], h[3]);
    *(ushort4*)(op + 384) = make_ushort4(l[0], l[1], l[2], l[3]);
  }
}

// ---------------- MFMA GEMM: Out[M][n] = Wc[M][KP] @ Xsplit, both k-contiguous ----------
// LDS tiles are [128 rows][32 k] bf16, LINEAR dest for global_load_lds; bank conflicts
// removed by chunk swizzle j -> j ^ ((row>>1)&3) applied to BOTH the per-lane global
// source offset (staging) and the ds_read address (frag load). (G-21 both-sides rule.)
// MODE 0: conv5 -> Y5t[n][1024] bf16 hi|lo, val=leaky(v*s+t).
// MODE 1: fused f1/f2/f3/sem fp32 stores, val=v*s+t, row ranges 0/128/256/512..532.
template <int KP, int KX, int XSTR, int MODE>
__global__ __launch_bounds__(256) void mgemm(
    const unsigned short* __restrict__ Wc, const unsigned short* __restrict__ Xt,
    float* __restrict__ O0, float* __restrict__ O1, float* __restrict__ O2,
    float* __restrict__ O3, unsigned short* __restrict__ Yt, const float* __restrict__ s,
    const float* __restrict__ t) {
  __shared__ unsigned short Al[128 * 32];
  __shared__ unsigned short Bl[128 * 32];
  const int tid = threadIdx.x;
  const int wid = tid >> 6, lane = tid & 63;
  const int col0 = blockIdx.x * 128;
  const int row0 = blockIdx.y * 128;
  const int wm = wid >> 1, wn = wid & 1;  // 2x2 waves, each 64x64
  f32x4 acc[4][4];
  f32x4 z = {0.f, 0.f, 0.f, 0.f};
#pragma unroll
  for (int i = 0; i < 4; i++)
#pragma unroll
    for (int j = 0; j < 4; j++) acc[i][j] = z;

  for (int k0 = 0; k0 < KP; k0 += 32) {
    int xoff = (k0 < 2 * KX) ? k0 : k0 - 2 * KX;
#pragma unroll
    for (int p = 0; p < 2; p++) {
      int idx = tid + p * 256;  // 0..511 : 16B chunk slots, LDS dest linear
      int r = idx >> 2, jj = idx & 3;
      int js = jj ^ ((r >> 1) & 3);  // pre-swizzled global source chunk
      __builtin_amdgcn_global_load_lds(
          (const __attribute__((address_space(1))) unsigned int*)(Wc + (size_t)(row0 + r) * KP +
                                                                  k0 + js * 8),
          (__attribute__((address_space(3))) unsigned int*)(Al + idx * 8), 16, 0, 0);
      __builtin_amdgcn_global_load_lds(
          (const __attribute__((address_space(1))) unsigned int*)(Xt + (size_t)(col0 + r) * XSTR +
                                                                  xoff + js * 8),
          (__attribute__((address_space(3))) unsigned int*)(Bl + idx * 8), 16, 0, 0);
    }
    __syncthreads();
    bf16x8 a[4], b[4];
#pragma unroll
    for (int f = 0; f < 4; f++) {
      int m = wm * 64 + f * 16 + (lane & 15);
      int ja = (lane >> 4) ^ ((m >> 1) & 3);
      a[f] = *(const bf16x8*)(Al + m * 32 + ja * 8);
      int n = wn * 64 + f * 16 + (lane & 15);
      int jb = (lane >> 4) ^ ((n >> 1) & 3);
      b[f] = *(const bf16x8*)(Bl + n * 32 + jb * 8);
    }
#pragma unroll
    for (int i = 0; i < 4; i++)
#pragma unroll
      for (int j = 0; j < 4; j++)
        acc[i][j] = __builtin_amdgcn_mfma_f32_16x16x32_bf16(a[i], b[j], acc[i][j], 0, 0, 0);
    __syncthreads();
  }

  // epilogue: lane holds D[4*(lane>>4)+r][lane&15] per 16x16 frag
#pragma unroll
  for (int j = 0; j < 4; j++) {
    int n = col0 + wn * 64 + j * 16 + (lane & 15);
    if (n >= COLS) continue;
#pragma unroll
    for (int i = 0; i < 4; i++) {
      int mb = row0 + wm * 64 + i * 16 + 4 * (lane >> 4);
      if (MODE == 0) {
        unsigned short h[4], l[4];
#pragma unroll
        for (int r = 0; r < 4; r++) {
          float v = acc[i][j][r] * s[mb + r] + t[mb + r];
          v = leaky(v);
          h[r] = f2b(v);
          l[r] = f2b(v - b2f(h[r]));
        }
        unsigned short* yp = Yt + (size_t)n * 1024 + mb;
        *(ushort4*)yp = make_ushort4(h[0], h[1], h[2], h[3]);
        *(ushort4*)(yp + 512) = make_ushort4(l[0], l[1], l[2], l[3]);
      } else {
        float4 v;
        v.x = acc[i][j][0] * s[mb + 0] + t[mb + 0];
        v.y = acc[i][j][1] * s[mb + 1] + t[mb + 1];
        v.z = acc[i][j][2] * s[mb + 2] + t[mb + 2];
        v.w = acc[i][j][3] * s[mb + 3] + t[mb + 3];
        float* p;
        if (mb < 128)
          p = O0 + (size_t)n * 128 + mb;
        else if (mb < 256)
          p = O1 + (size_t)n * 128 + (mb - 128);
        else if (mb < 512)
          p = O2 + (size_t)n * 256 + (mb - 256);
        else if (mb < 532)
          p = O3 + (size_t)n * 20 + (mb - 512);
        else
          continue;
        *(float4*)p = v;
      }
    }
  }
}

// ---------------- coords passthrough + zero masks ----------------
__global__ void misc_kernel(const float* __restrict__ coords, float* __restrict__ out_coords,
                            float* __restrict__ out_masks) {
  int i = blockIdx.x * blockDim.x + threadIdx.x;
  if (i < NBATCH * N_PTS * 3) out_coords[i] = coords[i];
  if (i < NBATCH * N_PTS) out_masks[i] = 0.f;
}

extern "C" void kernel_launch(void* const* d_in, const int* in_sizes, int n_in, void* d_out,
                              int out_size, void* d_ws, size_t ws_size, hipStream_t stream) {
  const float* coords = (const float*)d_in[0];
  const float* feats = (const float*)d_in[1];
  const float* ew1 = (const float*)d_in[2];
  const float* es1 = (const float*)d_in[3];
  const float* et1 = (const float*)d_in[4];
  const float* ew2 = (const float*)d_in[5];
  const float* es2 = (const float*)d_in[6];
  const float* et2 = (const float*)d_in[7];
  const float* ew3 = (const float*)d_in[8];
  const float* es3 = (const float*)d_in[9];
  const float* et3 = (const float*)d_in[10];
  const float* ew4 = (const float*)d_in[11];
  const float* es4 = (const float*)d_in[12];
  const float* et4 = (const float*)d_in[13];
  const float* w5 = (const float*)d_in[14];
  const float* s5 = (const float*)d_in[15];
  const float* t5 = (const float*)d_in[16];
  const float* fw1 = (const float*)d_in[17];
  const float* fs1 = (const float*)d_in[18];
  const float* ft1 = (const float*)d_in[19];
  const float* fw2 = (const float*)d_in[20];
  const float* fs2 = (const float*)d_in[21];
  const float* ft2 = (const float*)d_in[22];
  const float* fw3 = (const float*)d_in[23];
  const float* fs3 = (const float*)d_in[24];
  const float* ft3 = (const float*)d_in[25];
  const float* sem_w = (const float*)d_in[26];
  const float* sem_b = (const float*)d_in[27];
  float* out = (float*)d_out;
  float* ws = (float*)d_ws;

  // workspace layout (float offsets; total 21,452,736 f = 85.8 MB)
  float* X0 = ws;                                    // 80000
  float* WS1 = ws + 80000;                           // 512
  float* WS2 = ws + 80512;                           // 8192
  float* WS3 = ws + 88704;                           // 16384
  float* WS4 = ws + 105088;                          // 32768
  float* sF = ws + 137856;                           // 640
  float* tF = ws + 138496;                           // 640
  float* SWp = ws + 139136;                          // 10240
  float* Bp = ws + 149376;                           // 64
  unsigned short* Wc5 = (unsigned short*)(ws + 149440);   // 512*1152 ush
  unsigned short* WcF = (unsigned short*)(ws + 444352);   // 640*1536 ush
  unsigned short* XCt = (unsigned short*)(ws + 935872);   // 20096*768 ush
  float* AB = ws + 8652736;                          // 256*20000 f
  float* XC = ws + 13772736;                         // 384*20000 f
  // Y5t aliases AB..XC region (both dead after xpose_split): 20096*1024 ush
  unsigned short* Y5t = (unsigned short*)(ws + 8652736);

  // d_out layout (floats)
  float* out_f1 = out;                 // 2*10000*128
  float* out_f2 = out + 2560000;       // 2*10000*128
  float* out_f3 = out + 5120000;       // 2*10000*256
  float* out_coords = out + 10240000;  // 60000
  float* out_masks = out + 10300000;   // 20000
  float* out_sem = out + 10320000;     // 2*10000*20

  dim3 blk(256);
  const int GX = (COLS + 127) / 128;  // 157

  // pack + all EC weight folds in one launch (20000 + 28928 items)
  prep_all<<<dim3(192), blk, 0, stream>>>(coords, feats, X0, ew1, WS1, ew2, WS2, ew3, WS3, ew4,
                                          WS4);

  // EC chain (fp32, proven)
  gemm_kernel<4, 0><<<dim3(GX, 2), blk, 0, stream>>>(WS1, X0, AB, nullptr, nullptr, 0);
  edge_finish<<<dim3(10, 64, 2), blk, 0, stream>>>(AB, 64, es1, et1, XC);
  gemm_kernel<64, 0><<<dim3(GX, 2), blk, 0, stream>>>(WS2, XC, AB, nullptr, nullptr, 0);
  edge_finish<<<dim3(10, 64, 2), blk, 0, stream>>>(AB, 64, es2, et2, XC + (size_t)64 * COLS);
  gemm_kernel<64, 0><<<dim3(GX, 4), blk, 0, stream>>>(WS3, XC + (size_t)64 * COLS, AB, nullptr,
                                                      nullptr, 0);
  edge_finish<<<dim3(10, 128, 2), blk, 0, stream>>>(AB, 128, es3, et3, XC + (size_t)128 * COLS);
  gemm_kernel<128, 0><<<dim3(GX, 4), blk, 0, stream>>>(WS4, XC + (size_t)128 * COLS, AB, nullptr,
                                                       nullptr, 0);
  edge_finish<<<dim3(10, 128, 2), blk, 0, stream>>>(AB, 128, es4, et4, XC + (size_t)256 * COLS);

  // weight prep for MFMA path
  split_w5<<<dim3(768), blk, 0, stream>>>(w5, Wc5);
  sem_prep<<<dim3(40), blk, 0, stream>>>(sem_w, sem_b, fw3, fs3, ft3, SWp, Bp);
  split_wf<<<dim3(1280), blk, 0, stream>>>(fw1, fw2, fw3, SWp, fs1, ft1, fs2, ft2, fs3, ft3, Bp,
                                           WcF, sF, tF);

  // activations: XC -> point-major bf16 hi/lo
  xpose_split<<<dim3(313, 12), blk, 0, stream>>>(XC, XCt);

  // conv5: [512][1152] @ XCt -> Y5t (leaky, split bf16)  -- overwrites AB/XC region
  mgemm<1152, 384, 768, 0><<<dim3(GX, 4), blk, 0, stream>>>(Wc5, XCt, nullptr, nullptr, nullptr,
                                                            nullptr, Y5t, s5, t5);

  // fused f1|f2|f3|sem: [640][1536] @ Y5t -> d_out
  mgemm<1536, 512, 1024, 1><<<dim3(GX, 5), blk, 0, stream>>>(WcF, Y5t, out_f1, out_f2, out_f3,
                                                             out_sem, nullptr, sF, tF);

  misc_kernel<<<dim3(236), blk, 0, stream>>>(coords, out_coords, out_masks);
}

// Round 9
// 387.482 us; speedup vs baseline: 1.6427x; 1.0256x over previous
//
#include <hip/hip_runtime.h>

#define N_PTS 10000
#define NBATCH 2
#define COLS (N_PTS * NBATCH)

typedef __attribute__((ext_vector_type(8))) short bf16x8;
typedef __attribute__((ext_vector_type(4))) float f32x4;

static __device__ __forceinline__ float leaky(float v) { return v > 0.f ? v : 0.2f * v; }

static __device__ __forceinline__ unsigned short f2b(float x) {
  unsigned int u = __float_as_uint(x);
  unsigned int r = (u + 0x7fffu + ((u >> 16) & 1u)) >> 16;
  return (unsigned short)r;
}
static __device__ __forceinline__ float b2f(unsigned short h) {
  return __uint_as_float((unsigned int)h << 16);
}

// ---------------- fused prep: pack X0 + all 4 EC weight folds ----------------
static __device__ __forceinline__ void prep_one(const float* __restrict__ ew,
                                                float* __restrict__ WS, int O, int C, int i) {
  int o = i / C, c = i - o * C;
  float wa = ew[(size_t)o * 2 * C + c];
  float wb = ew[(size_t)o * 2 * C + C + c];
  WS[(size_t)o * C + c] = wa + wb;
  WS[(size_t)(O + o) * C + c] = wa;
}

__global__ void prep_all(const float* __restrict__ coords, const float* __restrict__ feats,
                         float* __restrict__ X0, const float* __restrict__ ew1,
                         float* __restrict__ WS1, const float* __restrict__ ew2,
                         float* __restrict__ WS2, const float* __restrict__ ew3,
                         float* __restrict__ WS3, const float* __restrict__ ew4,
                         float* __restrict__ WS4) {
  int i = blockIdx.x * 256 + threadIdx.x;
  if (i < COLS) {
    const float* cp = coords + (size_t)i * 3;
    X0[0 * COLS + i] = cp[0];
    X0[1 * COLS + i] = cp[1];
    X0[2 * COLS + i] = cp[2];
    X0[3 * COLS + i] = feats[(size_t)i * 4 + 3];
    return;
  }
  i -= COLS;
  if (i < 256) { prep_one(ew1, WS1, 64, 4, i); return; }
  i -= 256;
  if (i < 4096) { prep_one(ew2, WS2, 64, 64, i); return; }
  i -= 4096;
  if (i < 8192) { prep_one(ew3, WS3, 128, 64, i); return; }
  i -= 8192;
  if (i < 16384) { prep_one(ew4, WS4, 128, 128, i); return; }
}

// ---------------- fp32 GEMM (EC layers only): Out[M][COLS] = W[M][K] @ X[K][COLS] --------
template <int K, int MODE>
__global__ __launch_bounds__(256) void gemm_kernel(
    const float* __restrict__ W, const float* __restrict__ X, float* __restrict__ Out,
    const float* __restrict__ s, const float* __restrict__ t, int Cf) {
  __shared__ float Ws[32][68];
  __shared__ float Xs[32][132];
  const int tid = threadIdx.x;
  const int col0 = blockIdx.x * 128;
  const int row0 = blockIdx.y * 64;
  const int tn = tid & 31, tm = tid >> 5;
  float acc[8][4];
#pragma unroll
  for (int i = 0; i < 8; i++)
#pragma unroll
    for (int j = 0; j < 4; j++) acc[i][j] = 0.f;

  const bool colok = (col0 + tn * 4) < COLS;

  for (int k0 = 0; k0 < K; k0 += 32) {
    {
      int m = tid >> 2;
      int kq = (tid & 3) * 8;
      if ((K & 31) == 0) {
        const float* wp = W + (size_t)(row0 + m) * K + k0 + kq;
        float4 w0 = *(const float4*)wp;
        float4 w1 = *(const float4*)(wp + 4);
        Ws[kq + 0][m] = w0.x; Ws[kq + 1][m] = w0.y; Ws[kq + 2][m] = w0.z; Ws[kq + 3][m] = w0.w;
        Ws[kq + 4][m] = w1.x; Ws[kq + 5][m] = w1.y; Ws[kq + 6][m] = w1.z; Ws[kq + 7][m] = w1.w;
      } else {
#pragma unroll
        for (int j = 0; j < 8; j++) {
          int k = kq + j;
          Ws[k][m] = (k0 + k < K) ? W[(size_t)(row0 + m) * K + k0 + k] : 0.f;
        }
      }
    }
#pragma unroll
    for (int p = 0; p < 4; p++) {
      int idx = tid + p * 256;
      int k = idx >> 5;
      int n4 = (idx & 31) << 2;
      int col = col0 + n4;
      float4 v = make_float4(0.f, 0.f, 0.f, 0.f);
      if (k0 + k < K && col < COLS) v = *(const float4*)(X + (size_t)(k0 + k) * COLS + col);
      *(float4*)&Xs[k][n4] = v;
    }
    __syncthreads();
#pragma unroll
    for (int k = 0; k < 32; k++) {
      float a[8], b[4];
      *(float4*)&a[0] = *(const float4*)&Ws[k][tm * 8];
      *(float4*)&a[4] = *(const float4*)&Ws[k][tm * 8 + 4];
      *(float4*)&b[0] = *(const float4*)&Xs[k][tn * 4];
#pragma unroll
      for (int i = 0; i < 8; i++)
#pragma unroll
        for (int j = 0; j < 4; j++) acc[i][j] = fmaf(a[i], b[j], acc[i][j]);
    }
    __syncthreads();
  }

  if (colok) {
#pragma unroll
    for (int i = 0; i < 8; i++) {
      int row = row0 + tm * 8 + i;
      float4 v = make_float4(acc[i][0], acc[i][1], acc[i][2], acc[i][3]);
      *(float4*)(Out + (size_t)row * COLS + col0 + tn * 4) = v;
    }
  }
}

// ---------------- edge finish: out = leaky((A - slidemin20(Bt, circular)) * s + t) --------
__global__ __launch_bounds__(256) void edge_finish(const float* __restrict__ AB, int O,
                                                   const float* __restrict__ s,
                                                   const float* __restrict__ t,
                                                   float* __restrict__ Xout) {
  __shared__ float sh[1024 + 20];
  int o = blockIdx.y;
  int b = blockIdx.z;
  int n0 = blockIdx.x * 1024;
  int nb = min(1024, N_PTS - n0);
  const float* Bt = AB + (size_t)(O + o) * COLS + (size_t)b * N_PTS;
  int base = N_PTS - n0 - nb + 1;
  int L = nb + 19;
  for (int i = threadIdx.x; i < L; i += 256) {
    int p = base + i;
    if (p >= N_PTS) p -= N_PTS;
    sh[i] = Bt[p];
  }
  __syncthreads();
  const float* Arow = AB + (size_t)o * COLS + (size_t)b * N_PTS;
  float ss = s[o], tt = t[o];
  for (int d = threadIdx.x; d < nb; d += 256) {
    int w = nb - 1 - d;
    float mn = sh[w];
#pragma unroll
    for (int k = 1; k < 20; k++) mn = fminf(mn, sh[w + k]);
    float v = (Arow[n0 + d] - mn) * ss + tt;
    Xout[(size_t)o * COLS + (size_t)b * N_PTS + n0 + d] = leaky(v);
  }
}

// ---------------- fold sem head through Y5: SWp[20][512], biasp[20] ----------------
__global__ void sem_prep(const float* __restrict__ sem_w, const float* __restrict__ sem_b,
                         const float* __restrict__ fw3, const float* __restrict__ fs3,
                         const float* __restrict__ ft3, float* __restrict__ SWp,
                         float* __restrict__ biasp) {
  int i = blockIdx.x * blockDim.x + threadIdx.x;
  if (i < 20 * 512) {
    int cls = i / 512, k = i - cls * 512;
    float acc = 0.f;
    for (int c = 0; c < 256; c++) acc += sem_w[cls * 256 + c] * fs3[c] * fw3[(size_t)c * 512 + k];
    SWp[i] = acc;
  }
  if (i < 20) {
    float acc = sem_b[i];
    for (int c = 0; c < 256; c++) acc += sem_w[i * 256 + c] * ft3[c];
    biasp[i] = acc;
  }
}

// ------------- split conv5 weights: Wc[512][1152] = [hi | hi | lo] of w5[512][384] -------
__global__ void split_w5(const float* __restrict__ w5, unsigned short* __restrict__ Wc) {
  int i = blockIdx.x * 256 + threadIdx.x;
  if (i >= 512 * 384) return;
  int m = i / 384, k = i - m * 384;
  float w = w5[i];
  unsigned short hi = f2b(w);
  unsigned short lo = f2b(w - b2f(hi));
  unsigned short* row = Wc + (size_t)m * 1152;
  row[k] = hi;
  row[384 + k] = hi;
  row[768 + k] = lo;
}

// ------------- split fused-f weights: Wc[640][1536]; rows: fw1|fw2|fw3|SWp|zeros ---------
__global__ void split_wf(const float* __restrict__ fw1, const float* __restrict__ fw2,
                         const float* __restrict__ fw3, const float* __restrict__ SWp,
                         const float* __restrict__ fs1, const float* __restrict__ ft1,
                         const float* __restrict__ fs2, const float* __restrict__ ft2,
                         const float* __restrict__ fs3, const float* __restrict__ ft3,
                         const float* __restrict__ Bp, unsigned short* __restrict__ Wc,
                         float* __restrict__ sF, float* __restrict__ tF) {
  int i = blockIdx.x * 256 + threadIdx.x;
  if (i >= 640 * 512) return;
  int m = i >> 9, k = i & 511;
  float w = 0.f, sv = 0.f, tv = 0.f;
  if (m < 128) {
    w = fw1[(size_t)m * 512 + k]; sv = fs1[m]; tv = ft1[m];
  } else if (m < 256) {
    w = fw2[(size_t)(m - 128) * 512 + k]; sv = fs2[m - 128]; tv = ft2[m - 128];
  } else if (m < 512) {
    w = fw3[(size_t)(m - 256) * 512 + k]; sv = fs3[m - 256]; tv = ft3[m - 256];
  } else if (m < 532) {
    w = SWp[(size_t)(m - 512) * 512 + k]; sv = 1.f; tv = Bp[m - 512];
  }
  unsigned short hi = f2b(w);
  unsigned short lo = f2b(w - b2f(hi));
  unsigned short* row = Wc + (size_t)m * 1536;
  row[k] = hi;
  row[512 + k] = hi;
  row[1024 + k] = lo;
  if (k == 0) { sF[m] = sv; tF[m] = tv; }
}

// ------------- transpose+split XC[384][COLS] fp32 -> XCt[n][768] bf16 (hi|lo) ------------
__global__ __launch_bounds__(256) void xpose_split(const float* __restrict__ XC,
                                                   unsigned short* __restrict__ XCt) {
  __shared__ float tile[32][65];
  int n0 = blockIdx.x * 64;
  int c0 = blockIdx.y * 32;
#pragma unroll
  for (int i = 0; i < 8; i++) {
    int e = threadIdx.x + i * 256;
    int c = e >> 6, n = e & 63;
    float v = 0.f;
    if (n0 + n < COLS) v = XC[(size_t)(c0 + c) * COLS + n0 + n];
    tile[c][n] = v;
  }
  __syncthreads();
#pragma unroll
  for (int i = 0; i < 2; i++) {
    int e = threadIdx.x + i * 256;
    int n = e >> 3, cq = (e & 7) * 4;
    if (n0 + n >= COLS) continue;
    unsigned short h[4], l[4];
#pragma unroll
    for (int j = 0; j < 4; j++) {
      float v = tile[cq + j][n];
      h[j] = f2b(v);
      l[j] = f2b(v - b2f(h[j]));
    }
    unsigned short* op = XCt + (size_t)(n0 + n) * 768 + c0 + cq;
    *(ushort4*)op = make_ushort4(h[0], h[1], h[2], h[3]);
    *(ushort4*)(op + 384) = make_ushort4(l[0], l[1], l[2], l[3]);
  }
}

// ---------------- MFMA GEMM, depth-2 pipelined (T3/T4) ----------------
// 3 LDS buffer pairs; raw s_barrier (no compiler vmcnt(0) drain); counted
// vmcnt(4) keeps the next tile's 4 global_load_lds in flight across the
// barrier. Chunk swizzle j -> j ^ ((row>>1)&3) on BOTH global source and
// ds_read (G-21) keeps frag reads bank-conflict-free.
// Buffer rotation t%3: STAGE(t+2) issued in body t targets buf[(t+2)%3],
// last read in body t-1 (all waves past barrier t => safe; 1 barrier/step).
// MODE 0: conv5 -> Y5t[n][1024] bf16 hi|lo, val=leaky(v*s+t).
// MODE 1: fused f1/f2/f3/sem fp32 stores, val=v*s+t, rows 0/128/256/512..532.
template <int KP, int KX, int XSTR, int MODE>
__global__ __launch_bounds__(256) void mgemm(
    const unsigned short* __restrict__ Wc, const unsigned short* __restrict__ Xt,
    float* __restrict__ O0, float* __restrict__ O1, float* __restrict__ O2,
    float* __restrict__ O3, unsigned short* __restrict__ Yt, const float* __restrict__ s,
    const float* __restrict__ t) {
  __shared__ unsigned short Al[3][128 * 32];
  __shared__ unsigned short Bl[3][128 * 32];
  const int tid = threadIdx.x;
  const int wid = tid >> 6, lane = tid & 63;
  const int col0 = blockIdx.x * 128;
  const int row0 = blockIdx.y * 128;
  const int wm = wid >> 1, wn = wid & 1;  // 2x2 waves, each 64x64
  f32x4 acc[4][4];
  f32x4 z = {0.f, 0.f, 0.f, 0.f};
#pragma unroll
  for (int i = 0; i < 4; i++)
#pragma unroll
    for (int j = 0; j < 4; j++) acc[i][j] = z;

  constexpr int NT = KP / 32;

  auto stage = [&](int buf, int kst) {
    int k0s = kst * 32;
    int xoffs = (k0s < 2 * KX) ? k0s : k0s - 2 * KX;
#pragma unroll
    for (int p = 0; p < 2; p++) {
      int idx = tid + p * 256;  // 0..511 : 16B chunk slots, LDS dest linear
      int r = idx >> 2, jj = idx & 3;
      int js = jj ^ ((r >> 1) & 3);  // pre-swizzled global source chunk
      __builtin_amdgcn_global_load_lds(
          (const __attribute__((address_space(1))) unsigned int*)(Wc + (size_t)(row0 + r) * KP +
                                                                  k0s + js * 8),
          (__attribute__((address_space(3))) unsigned int*)(&Al[buf][idx * 8]), 16, 0, 0);
      __builtin_amdgcn_global_load_lds(
          (const __attribute__((address_space(1))) unsigned int*)(Xt + (size_t)(col0 + r) * XSTR +
                                                                  xoffs + js * 8),
          (__attribute__((address_space(3))) unsigned int*)(&Bl[buf][idx * 8]), 16, 0, 0);
    }
  };

  auto compute = [&](int buf) {
    bf16x8 a[4], b[4];
#pragma unroll
    for (int f = 0; f < 4; f++) {
      int m = wm * 64 + f * 16 + (lane & 15);
      int ja = (lane >> 4) ^ ((m >> 1) & 3);
      a[f] = *(const bf16x8*)(&Al[buf][m * 32 + ja * 8]);
      int n = wn * 64 + f * 16 + (lane & 15);
      int jb = (lane >> 4) ^ ((n >> 1) & 3);
      b[f] = *(const bf16x8*)(&Bl[buf][n * 32 + jb * 8]);
    }
#pragma unroll
    for (int i = 0; i < 4; i++)
#pragma unroll
      for (int j = 0; j < 4; j++)
        acc[i][j] = __builtin_amdgcn_mfma_f32_16x16x32_bf16(a[i], b[j], acc[i][j], 0, 0, 0);
  };

  stage(0, 0);
  stage(1, 1);
#pragma unroll 1
  for (int tt = 0; tt < NT - 1; ++tt) {
    asm volatile("s_waitcnt vmcnt(4)" ::: "memory");  // own step-tt loads landed
    __builtin_amdgcn_s_barrier();                      // whole tile resident
    if (tt + 2 < NT) stage((tt + 2) % 3, tt + 2);      // prefetch depth 2
    compute(tt % 3);
  }
  asm volatile("s_waitcnt vmcnt(0)" ::: "memory");
  __builtin_amdgcn_s_barrier();
  compute((NT - 1) % 3);

  // epilogue: lane holds D[4*(lane>>4)+r][lane&15] per 16x16 frag
#pragma unroll
  for (int j = 0; j < 4; j++) {
    int n = col0 + wn * 64 + j * 16 + (lane & 15);
    if (n >= COLS) continue;
#pragma unroll
    for (int i = 0; i < 4; i++) {
      int mb = row0 + wm * 64 + i * 16 + 4 * (lane >> 4);
      if (MODE == 0) {
        unsigned short h[4], l[4];
#pragma unroll
        for (int r = 0; r < 4; r++) {
          float v = acc[i][j][r] * s[mb + r] + t[mb + r];
          v = leaky(v);
          h[r] = f2b(v);
          l[r] = f2b(v - b2f(h[r]));
        }
        unsigned short* yp = Yt + (size_t)n * 1024 + mb;
        *(ushort4*)yp = make_ushort4(h[0], h[1], h[2], h[3]);
        *(ushort4*)(yp + 512) = make_ushort4(l[0], l[1], l[2], l[3]);
      } else {
        float4 v;
        v.x = acc[i][j][0] * s[mb + 0] + t[mb + 0];
        v.y = acc[i][j][1] * s[mb + 1] + t[mb + 1];
        v.z = acc[i][j][2] * s[mb + 2] + t[mb + 2];
        v.w = acc[i][j][3] * s[mb + 3] + t[mb + 3];
        float* p;
        if (mb < 128)
          p = O0 + (size_t)n * 128 + mb;
        else if (mb < 256)
          p = O1 + (size_t)n * 128 + (mb - 128);
        else if (mb < 512)
          p = O2 + (size_t)n * 256 + (mb - 256);
        else if (mb < 532)
          p = O3 + (size_t)n * 20 + (mb - 512);
        else
          continue;
        *(float4*)p = v;
      }
    }
  }
}

// ---------------- coords passthrough + zero masks ----------------
__global__ void misc_kernel(const float* __restrict__ coords, float* __restrict__ out_coords,
                            float* __restrict__ out_masks) {
  int i = blockIdx.x * blockDim.x + threadIdx.x;
  if (i < NBATCH * N_PTS * 3) out_coords[i] = coords[i];
  if (i < NBATCH * N_PTS) out_masks[i] = 0.f;
}

extern "C" void kernel_launch(void* const* d_in, const int* in_sizes, int n_in, void* d_out,
                              int out_size, void* d_ws, size_t ws_size, hipStream_t stream) {
  const float* coords = (const float*)d_in[0];
  const float* feats = (const float*)d_in[1];
  const float* ew1 = (const float*)d_in[2];
  const float* es1 = (const float*)d_in[3];
  const float* et1 = (const float*)d_in[4];
  const float* ew2 = (const float*)d_in[5];
  const float* es2 = (const float*)d_in[6];
  const float* et2 = (const float*)d_in[7];
  const float* ew3 = (const float*)d_in[8];
  const float* es3 = (const float*)d_in[9];
  const float* et3 = (const float*)d_in[10];
  const float* ew4 = (const float*)d_in[11];
  const float* es4 = (const float*)d_in[12];
  const float* et4 = (const float*)d_in[13];
  const float* w5 = (const float*)d_in[14];
  const float* s5 = (const float*)d_in[15];
  const float* t5 = (const float*)d_in[16];
  const float* fw1 = (const float*)d_in[17];
  const float* fs1 = (const float*)d_in[18];
  const float* ft1 = (const float*)d_in[19];
  const float* fw2 = (const float*)d_in[20];
  const float* fs2 = (const float*)d_in[21];
  const float* ft2 = (const float*)d_in[22];
  const float* fw3 = (const float*)d_in[23];
  const float* fs3 = (const float*)d_in[24];
  const float* ft3 = (const float*)d_in[25];
  const float* sem_w = (const float*)d_in[26];
  const float* sem_b = (const float*)d_in[27];
  float* out = (float*)d_out;
  float* ws = (float*)d_ws;

  // workspace layout (float offsets; total 21,452,736 f = 85.8 MB)
  float* X0 = ws;                                    // 80000
  float* WS1 = ws + 80000;                           // 512
  float* WS2 = ws + 80512;                           // 8192
  float* WS3 = ws + 88704;                           // 16384
  float* WS4 = ws + 105088;                          // 32768
  float* sF = ws + 137856;                           // 640
  float* tF = ws + 138496;                           // 640
  float* SWp = ws + 139136;                          // 10240
  float* Bp = ws + 149376;                           // 64
  unsigned short* Wc5 = (unsigned short*)(ws + 149440);   // 512*1152 ush
  unsigned short* WcF = (unsigned short*)(ws + 444352);   // 640*1536 ush
  unsigned short* XCt = (unsigned short*)(ws + 935872);   // 20096*768 ush
  float* AB = ws + 8652736;                          // 256*20000 f
  float* XC = ws + 13772736;                         // 384*20000 f
  // Y5t aliases AB..XC region (both dead after xpose_split): 20096*1024 ush
  unsigned short* Y5t = (unsigned short*)(ws + 8652736);

  // d_out layout (floats)
  float* out_f1 = out;                 // 2*10000*128
  float* out_f2 = out + 2560000;       // 2*10000*128
  float* out_f3 = out + 5120000;       // 2*10000*256
  float* out_coords = out + 10240000;  // 60000
  float* out_masks = out + 10300000;   // 20000
  float* out_sem = out + 10320000;     // 2*10000*20

  dim3 blk(256);
  const int GX = (COLS + 127) / 128;  // 157

  // pack + all EC weight folds in one launch (20000 + 28928 items)
  prep_all<<<dim3(192), blk, 0, stream>>>(coords, feats, X0, ew1, WS1, ew2, WS2, ew3, WS3, ew4,
                                          WS4);

  // EC chain (fp32, proven)
  gemm_kernel<4, 0><<<dim3(GX, 2), blk, 0, stream>>>(WS1, X0, AB, nullptr, nullptr, 0);
  edge_finish<<<dim3(10, 64, 2), blk, 0, stream>>>(AB, 64, es1, et1, XC);
  gemm_kernel<64, 0><<<dim3(GX, 2), blk, 0, stream>>>(WS2, XC, AB, nullptr, nullptr, 0);
  edge_finish<<<dim3(10, 64, 2), blk, 0, stream>>>(AB, 64, es2, et2, XC + (size_t)64 * COLS);
  gemm_kernel<64, 0><<<dim3(GX, 4), blk, 0, stream>>>(WS3, XC + (size_t)64 * COLS, AB, nullptr,
                                                      nullptr, 0);
  edge_finish<<<dim3(10, 128, 2), blk, 0, stream>>>(AB, 128, es3, et3, XC + (size_t)128 * COLS);
  gemm_kernel<128, 0><<<dim3(GX, 4), blk, 0, stream>>>(WS4, XC + (size_t)128 * COLS, AB, nullptr,
                                                       nullptr, 0);
  edge_finish<<<dim3(10, 128, 2), blk, 0, stream>>>(AB, 128, es4, et4, XC + (size_t)256 * COLS);

  // weight prep for MFMA path
  split_w5<<<dim3(768), blk, 0, stream>>>(w5, Wc5);
  sem_prep<<<dim3(40), blk, 0, stream>>>(sem_w, sem_b, fw3, fs3, ft3, SWp, Bp);
  split_wf<<<dim3(1280), blk, 0, stream>>>(fw1, fw2, fw3, SWp, fs1, ft1, fs2, ft2, fs3, ft3, Bp,
                                           WcF, sF, tF);

  // activations: XC -> point-major bf16 hi/lo
  xpose_split<<<dim3(313, 12), blk, 0, stream>>>(XC, XCt);

  // conv5: [512][1152] @ XCt -> Y5t (leaky, split bf16)  -- overwrites AB/XC region
  mgemm<1152, 384, 768, 0><<<dim3(GX, 4), blk, 0, stream>>>(Wc5, XCt, nullptr, nullptr, nullptr,
                                                            nullptr, Y5t, s5, t5);

  // fused f1|f2|f3|sem: [640][1536] @ Y5t -> d_out
  mgemm<1536, 512, 1024, 1><<<dim3(GX, 5), blk, 0, stream>>>(WcF, Y5t, out_f1, out_f2, out_f3,
                                                             out_sem, nullptr, sF, tF);

  misc_kernel<<<dim3(236), blk, 0, stream>>>(coords, out_coords, out_masks);
}

// Round 10
// 382.804 us; speedup vs baseline: 1.6627x; 1.0122x over previous
//
#include <hip/hip_runtime.h>

#define N_PTS 10000
#define NBATCH 2
#define COLS (N_PTS * NBATCH)

typedef __attribute__((ext_vector_type(8))) short bf16x8;
typedef __attribute__((ext_vector_type(4))) float f32x4;

static __device__ __forceinline__ float leaky(float v) { return v > 0.f ? v : 0.2f * v; }

static __device__ __forceinline__ unsigned short f2b(float x) {
  unsigned int u = __float_as_uint(x);
  unsigned int r = (u + 0x7fffu + ((u >> 16) & 1u)) >> 16;
  return (unsigned short)r;
}
static __device__ __forceinline__ float b2f(unsigned short h) {
  return __uint_as_float((unsigned int)h << 16);
}

// ---------------- fused prep: pack X0 + all 4 EC weight folds ----------------
static __device__ __forceinline__ void prep_one(const float* __restrict__ ew,
                                                float* __restrict__ WS, int O, int C, int i) {
  int o = i / C, c = i - o * C;
  float wa = ew[(size_t)o * 2 * C + c];
  float wb = ew[(size_t)o * 2 * C + C + c];
  WS[(size_t)o * C + c] = wa + wb;
  WS[(size_t)(O + o) * C + c] = wa;
}

__global__ void prep_all(const float* __restrict__ coords, const float* __restrict__ feats,
                         float* __restrict__ X0, const float* __restrict__ ew1,
                         float* __restrict__ WS1, const float* __restrict__ ew2,
                         float* __restrict__ WS2, const float* __restrict__ ew3,
                         float* __restrict__ WS3, const float* __restrict__ ew4,
                         float* __restrict__ WS4) {
  int i = blockIdx.x * 256 + threadIdx.x;
  if (i < COLS) {
    const float* cp = coords + (size_t)i * 3;
    X0[0 * COLS + i] = cp[0];
    X0[1 * COLS + i] = cp[1];
    X0[2 * COLS + i] = cp[2];
    X0[3 * COLS + i] = feats[(size_t)i * 4 + 3];
    return;
  }
  i -= COLS;
  if (i < 256) { prep_one(ew1, WS1, 64, 4, i); return; }
  i -= 256;
  if (i < 4096) { prep_one(ew2, WS2, 64, 64, i); return; }
  i -= 4096;
  if (i < 8192) { prep_one(ew3, WS3, 128, 64, i); return; }
  i -= 8192;
  if (i < 16384) { prep_one(ew4, WS4, 128, 128, i); return; }
}

// ---------------- fp32 GEMM (EC layers only): Out[M][COLS] = W[M][K] @ X[K][COLS] --------
template <int K, int MODE>
__global__ __launch_bounds__(256) void gemm_kernel(
    const float* __restrict__ W, const float* __restrict__ X, float* __restrict__ Out,
    const float* __restrict__ s, const float* __restrict__ t, int Cf) {
  __shared__ float Ws[32][68];
  __shared__ float Xs[32][132];
  const int tid = threadIdx.x;
  const int col0 = blockIdx.x * 128;
  const int row0 = blockIdx.y * 64;
  const int tn = tid & 31, tm = tid >> 5;
  float acc[8][4];
#pragma unroll
  for (int i = 0; i < 8; i++)
#pragma unroll
    for (int j = 0; j < 4; j++) acc[i][j] = 0.f;

  const bool colok = (col0 + tn * 4) < COLS;

  for (int k0 = 0; k0 < K; k0 += 32) {
    {
      int m = tid >> 2;
      int kq = (tid & 3) * 8;
      if ((K & 31) == 0) {
        const float* wp = W + (size_t)(row0 + m) * K + k0 + kq;
        float4 w0 = *(const float4*)wp;
        float4 w1 = *(const float4*)(wp + 4);
        Ws[kq + 0][m] = w0.x; Ws[kq + 1][m] = w0.y; Ws[kq + 2][m] = w0.z; Ws[kq + 3][m] = w0.w;
        Ws[kq + 4][m] = w1.x; Ws[kq + 5][m] = w1.y; Ws[kq + 6][m] = w1.z; Ws[kq + 7][m] = w1.w;
      } else {
#pragma unroll
        for (int j = 0; j < 8; j++) {
          int k = kq + j;
          Ws[k][m] = (k0 + k < K) ? W[(size_t)(row0 + m) * K + k0 + k] : 0.f;
        }
      }
    }
#pragma unroll
    for (int p = 0; p < 4; p++) {
      int idx = tid + p * 256;
      int k = idx >> 5;
      int n4 = (idx & 31) << 2;
      int col = col0 + n4;
      float4 v = make_float4(0.f, 0.f, 0.f, 0.f);
      if (k0 + k < K && col < COLS) v = *(const float4*)(X + (size_t)(k0 + k) * COLS + col);
      *(float4*)&Xs[k][n4] = v;
    }
    __syncthreads();
#pragma unroll
    for (int k = 0; k < 32; k++) {
      float a[8], b[4];
      *(float4*)&a[0] = *(const float4*)&Ws[k][tm * 8];
      *(float4*)&a[4] = *(const float4*)&Ws[k][tm * 8 + 4];
      *(float4*)&b[0] = *(const float4*)&Xs[k][tn * 4];
#pragma unroll
      for (int i = 0; i < 8; i++)
#pragma unroll
        for (int j = 0; j < 4; j++) acc[i][j] = fmaf(a[i], b[j], acc[i][j]);
    }
    __syncthreads();
  }

  if (colok) {
#pragma unroll
    for (int i = 0; i < 8; i++) {
      int row = row0 + tm * 8 + i;
      float4 v = make_float4(acc[i][0], acc[i][1], acc[i][2], acc[i][3]);
      *(float4*)(Out + (size_t)row * COLS + col0 + tn * 4) = v;
    }
  }
}

// ---------------- edge finish: out = leaky((A - slidemin20(Bt, circular)) * s + t) --------
__global__ __launch_bounds__(256) void edge_finish(const float* __restrict__ AB, int O,
                                                   const float* __restrict__ s,
                                                   const float* __restrict__ t,
                                                   float* __restrict__ Xout) {
  __shared__ float sh[1024 + 20];
  int o = blockIdx.y;
  int b = blockIdx.z;
  int n0 = blockIdx.x * 1024;
  int nb = min(1024, N_PTS - n0);
  const float* Bt = AB + (size_t)(O + o) * COLS + (size_t)b * N_PTS;
  int base = N_PTS - n0 - nb + 1;
  int L = nb + 19;
  for (int i = threadIdx.x; i < L; i += 256) {
    int p = base + i;
    if (p >= N_PTS) p -= N_PTS;
    sh[i] = Bt[p];
  }
  __syncthreads();
  const float* Arow = AB + (size_t)o * COLS + (size_t)b * N_PTS;
  float ss = s[o], tt = t[o];
  for (int d = threadIdx.x; d < nb; d += 256) {
    int w = nb - 1 - d;
    float mn = sh[w];
#pragma unroll
    for (int k = 1; k < 20; k++) mn = fminf(mn, sh[w + k]);
    float v = (Arow[n0 + d] - mn) * ss + tt;
    Xout[(size_t)o * COLS + (size_t)b * N_PTS + n0 + d] = leaky(v);
  }
}

// ---------------- fold sem head through Y5: SWp[20][512], biasp[20] ----------------
__global__ void sem_prep(const float* __restrict__ sem_w, const float* __restrict__ sem_b,
                         const float* __restrict__ fw3, const float* __restrict__ fs3,
                         const float* __restrict__ ft3, float* __restrict__ SWp,
                         float* __restrict__ biasp) {
  int i = blockIdx.x * blockDim.x + threadIdx.x;
  if (i < 20 * 512) {
    int cls = i / 512, k = i - cls * 512;
    float acc = 0.f;
    for (int c = 0; c < 256; c++) acc += sem_w[cls * 256 + c] * fs3[c] * fw3[(size_t)c * 512 + k];
    SWp[i] = acc;
  }
  if (i < 20) {
    float acc = sem_b[i];
    for (int c = 0; c < 256; c++) acc += sem_w[i * 256 + c] * ft3[c];
    biasp[i] = acc;
  }
}

// ------------- split conv5 weights: Wc[512][1152] = [hi | hi | lo] of w5[512][384] -------
__global__ void split_w5(const float* __restrict__ w5, unsigned short* __restrict__ Wc) {
  int i = blockIdx.x * 256 + threadIdx.x;
  if (i >= 512 * 384) return;
  int m = i / 384, k = i - m * 384;
  float w = w5[i];
  unsigned short hi = f2b(w);
  unsigned short lo = f2b(w - b2f(hi));
  unsigned short* row = Wc + (size_t)m * 1152;
  row[k] = hi;
  row[384 + k] = hi;
  row[768 + k] = lo;
}

// ------------- split fused-f weights: Wc[640][1536]; rows: fw1|fw2|fw3|SWp|zeros ---------
__global__ void split_wf(const float* __restrict__ fw1, const float* __restrict__ fw2,
                         const float* __restrict__ fw3, const float* __restrict__ SWp,
                         const float* __restrict__ fs1, const float* __restrict__ ft1,
                         const float* __restrict__ fs2, const float* __restrict__ ft2,
                         const float* __restrict__ fs3, const float* __restrict__ ft3,
                         const float* __restrict__ Bp, unsigned short* __restrict__ Wc,
                         float* __restrict__ sF, float* __restrict__ tF) {
  int i = blockIdx.x * 256 + threadIdx.x;
  if (i >= 640 * 512) return;
  int m = i >> 9, k = i & 511;
  float w = 0.f, sv = 0.f, tv = 0.f;
  if (m < 128) {
    w = fw1[(size_t)m * 512 + k]; sv = fs1[m]; tv = ft1[m];
  } else if (m < 256) {
    w = fw2[(size_t)(m - 128) * 512 + k]; sv = fs2[m - 128]; tv = ft2[m - 128];
  } else if (m < 512) {
    w = fw3[(size_t)(m - 256) * 512 + k]; sv = fs3[m - 256]; tv = ft3[m - 256];
  } else if (m < 532) {
    w = SWp[(size_t)(m - 512) * 512 + k]; sv = 1.f; tv = Bp[m - 512];
  }
  unsigned short hi = f2b(w);
  unsigned short lo = f2b(w - b2f(hi));
  unsigned short* row = Wc + (size_t)m * 1536;
  row[k] = hi;
  row[512 + k] = hi;
  row[1024 + k] = lo;
  if (k == 0) { sF[m] = sv; tF[m] = tv; }
}

// ------------- transpose+split XC[384][COLS] fp32 -> XCt[n][768] bf16 (hi|lo) ------------
__global__ __launch_bounds__(256) void xpose_split(const float* __restrict__ XC,
                                                   unsigned short* __restrict__ XCt) {
  __shared__ float tile[32][65];
  int n0 = blockIdx.x * 64;
  int c0 = blockIdx.y * 32;
#pragma unroll
  for (int i = 0; i < 8; i++) {
    int e = threadIdx.x + i * 256;
    int c = e >> 6, n = e & 63;
    float v = 0.f;
    if (n0 + n < COLS) v = XC[(size_t)(c0 + c) * COLS + n0 + n];
    tile[c][n] = v;
  }
  __syncthreads();
#pragma unroll
  for (int i = 0; i < 2; i++) {
    int e = threadIdx.x + i * 256;
    int n = e >> 3, cq = (e & 7) * 4;
    if (n0 + n >= COLS) continue;
    unsigned short h[4], l[4];
#pragma unroll
    for (int j = 0; j < 4; j++) {
      float v = tile[cq + j][n];
      h[j] = f2b(v);
      l[j] = f2b(v - b2f(h[j]));
    }
    unsigned short* op = XCt + (size_t)(n0 + n) * 768 + c0 + cq;
    *(ushort4*)op = make_ushort4(h[0], h[1], h[2], h[3]);
    *(ushort4*)(op + 384) = make_ushort4(l[0], l[1], l[2], l[3]);
  }
}

// ---------------- MFMA GEMM (single-buffer, r7 body) + T1 XCD col-tile swizzle ----------
// 1-D grid of GX*MR blocks. Bijective chunked remap (m204): consecutive tile index t
// lands on ONE XCD; t enumerates (col-tile, row-tile) with row fastest => all MR
// row-blocks of a column tile share that XCD's L2 => Y5t/XCt column slab fetched once.
// Chunk swizzle j -> j ^ ((row>>1)&3) on BOTH global source and ds_read (G-21).
// MODE 0: conv5 -> Y5t[n][1024] bf16 hi|lo, val=leaky(v*s+t).
// MODE 1: fused f1/f2/f3/sem fp32 stores, val=v*s+t, rows 0/128/256/512..532.
template <int KP, int KX, int XSTR, int MODE, int MR>
__global__ __launch_bounds__(256) void mgemm(
    const unsigned short* __restrict__ Wc, const unsigned short* __restrict__ Xt,
    float* __restrict__ O0, float* __restrict__ O1, float* __restrict__ O2,
    float* __restrict__ O3, unsigned short* __restrict__ Yt, const float* __restrict__ s,
    const float* __restrict__ t) {
  __shared__ unsigned short Al[128 * 32];
  __shared__ unsigned short Bl[128 * 32];
  const int tid = threadIdx.x;
  const int wid = tid >> 6, lane = tid & 63;
  // --- T1 swizzle: blockIdx -> tile t, grouped per XCD ---
  const int B = gridDim.x;
  const int q = B >> 3, r = B & 7;
  const int xcd = blockIdx.x & 7, jj0 = blockIdx.x >> 3;
  const int tIdx = xcd * q + min(xcd, r) + jj0;
  const int col0 = (tIdx / MR) * 128;
  const int row0 = (tIdx - (tIdx / MR) * MR) * 128;
  const int wm = wid >> 1, wn = wid & 1;  // 2x2 waves, each 64x64
  f32x4 acc[4][4];
  f32x4 z = {0.f, 0.f, 0.f, 0.f};
#pragma unroll
  for (int i = 0; i < 4; i++)
#pragma unroll
    for (int j = 0; j < 4; j++) acc[i][j] = z;

  for (int k0 = 0; k0 < KP; k0 += 32) {
    int xoff = (k0 < 2 * KX) ? k0 : k0 - 2 * KX;
#pragma unroll
    for (int p = 0; p < 2; p++) {
      int idx = tid + p * 256;  // 0..511 : 16B chunk slots, LDS dest linear
      int rr = idx >> 2, jc = idx & 3;
      int js = jc ^ ((rr >> 1) & 3);  // pre-swizzled global source chunk
      __builtin_amdgcn_global_load_lds(
          (const __attribute__((address_space(1))) unsigned int*)(Wc + (size_t)(row0 + rr) * KP +
                                                                  k0 + js * 8),
          (__attribute__((address_space(3))) unsigned int*)(Al + idx * 8), 16, 0, 0);
      __builtin_amdgcn_global_load_lds(
          (const __attribute__((address_space(1))) unsigned int*)(Xt + (size_t)(col0 + rr) * XSTR +
                                                                  xoff + js * 8),
          (__attribute__((address_space(3))) unsigned int*)(Bl + idx * 8), 16, 0, 0);
    }
    __syncthreads();
    bf16x8 a[4], b[4];
#pragma unroll
    for (int f = 0; f < 4; f++) {
      int m = wm * 64 + f * 16 + (lane & 15);
      int ja = (lane >> 4) ^ ((m >> 1) & 3);
      a[f] = *(const bf16x8*)(Al + m * 32 + ja * 8);
      int n = wn * 64 + f * 16 + (lane & 15);
      int jb = (lane >> 4) ^ ((n >> 1) & 3);
      b[f] = *(const bf16x8*)(Bl + n * 32 + jb * 8);
    }
#pragma unroll
    for (int i = 0; i < 4; i++)
#pragma unroll
      for (int j = 0; j < 4; j++)
        acc[i][j] = __builtin_amdgcn_mfma_f32_16x16x32_bf16(a[i], b[j], acc[i][j], 0, 0, 0);
    __syncthreads();
  }

  // epilogue: lane holds D[4*(lane>>4)+r][lane&15] per 16x16 frag
#pragma unroll
  for (int j = 0; j < 4; j++) {
    int n = col0 + wn * 64 + j * 16 + (lane & 15);
    if (n >= COLS) continue;
#pragma unroll
    for (int i = 0; i < 4; i++) {
      int mb = row0 + wm * 64 + i * 16 + 4 * (lane >> 4);
      if (MODE == 0) {
        unsigned short h[4], l[4];
#pragma unroll
        for (int rr = 0; rr < 4; rr++) {
          float v = acc[i][j][rr] * s[mb + rr] + t[mb + rr];
          v = leaky(v);
          h[rr] = f2b(v);
          l[rr] = f2b(v - b2f(h[rr]));
        }
        unsigned short* yp = Yt + (size_t)n * 1024 + mb;
        *(ushort4*)yp = make_ushort4(h[0], h[1], h[2], h[3]);
        *(ushort4*)(yp + 512) = make_ushort4(l[0], l[1], l[2], l[3]);
      } else {
        float4 v;
        v.x = acc[i][j][0] * s[mb + 0] + t[mb + 0];
        v.y = acc[i][j][1] * s[mb + 1] + t[mb + 1];
        v.z = acc[i][j][2] * s[mb + 2] + t[mb + 2];
        v.w = acc[i][j][3] * s[mb + 3] + t[mb + 3];
        float* p;
        if (mb < 128)
          p = O0 + (size_t)n * 128 + mb;
        else if (mb < 256)
          p = O1 + (size_t)n * 128 + (mb - 128);
        else if (mb < 512)
          p = O2 + (size_t)n * 256 + (mb - 256);
        else if (mb < 532)
          p = O3 + (size_t)n * 20 + (mb - 512);
        else
          continue;
        *(float4*)p = v;
      }
    }
  }
}

// ---------------- coords passthrough + zero masks ----------------
__global__ void misc_kernel(const float* __restrict__ coords, float* __restrict__ out_coords,
                            float* __restrict__ out_masks) {
  int i = blockIdx.x * blockDim.x + threadIdx.x;
  if (i < NBATCH * N_PTS * 3) out_coords[i] = coords[i];
  if (i < NBATCH * N_PTS) out_masks[i] = 0.f;
}

extern "C" void kernel_launch(void* const* d_in, const int* in_sizes, int n_in, void* d_out,
                              int out_size, void* d_ws, size_t ws_size, hipStream_t stream) {
  const float* coords = (const float*)d_in[0];
  const float* feats = (const float*)d_in[1];
  const float* ew1 = (const float*)d_in[2];
  const float* es1 = (const float*)d_in[3];
  const float* et1 = (const float*)d_in[4];
  const float* ew2 = (const float*)d_in[5];
  const float* es2 = (const float*)d_in[6];
  const float* et2 = (const float*)d_in[7];
  const float* ew3 = (const float*)d_in[8];
  const float* es3 = (const float*)d_in[9];
  const float* et3 = (const float*)d_in[10];
  const float* ew4 = (const float*)d_in[11];
  const float* es4 = (const float*)d_in[12];
  const float* et4 = (const float*)d_in[13];
  const float* w5 = (const float*)d_in[14];
  const float* s5 = (const float*)d_in[15];
  const float* t5 = (const float*)d_in[16];
  const float* fw1 = (const float*)d_in[17];
  const float* fs1 = (const float*)d_in[18];
  const float* ft1 = (const float*)d_in[19];
  const float* fw2 = (const float*)d_in[20];
  const float* fs2 = (const float*)d_in[21];
  const float* ft2 = (const float*)d_in[22];
  const float* fw3 = (const float*)d_in[23];
  const float* fs3 = (const float*)d_in[24];
  const float* ft3 = (const float*)d_in[25];
  const float* sem_w = (const float*)d_in[26];
  const float* sem_b = (const float*)d_in[27];
  float* out = (float*)d_out;
  float* ws = (float*)d_ws;

  // workspace layout (float offsets; total 21,452,736 f = 85.8 MB)
  float* X0 = ws;                                    // 80000
  float* WS1 = ws + 80000;                           // 512
  float* WS2 = ws + 80512;                           // 8192
  float* WS3 = ws + 88704;                           // 16384
  float* WS4 = ws + 105088;                          // 32768
  float* sF = ws + 137856;                           // 640
  float* tF = ws + 138496;                           // 640
  float* SWp = ws + 139136;                          // 10240
  float* Bp = ws + 149376;                           // 64
  unsigned short* Wc5 = (unsigned short*)(ws + 149440);   // 512*1152 ush
  unsigned short* WcF = (unsigned short*)(ws + 444352);   // 640*1536 ush
  unsigned short* XCt = (unsigned short*)(ws + 935872);   // 20096*768 ush
  float* AB = ws + 8652736;                          // 256*20000 f
  float* XC = ws + 13772736;                         // 384*20000 f
  // Y5t aliases AB..XC region (both dead after xpose_split): 20096*1024 ush
  unsigned short* Y5t = (unsigned short*)(ws + 8652736);

  // d_out layout (floats)
  float* out_f1 = out;                 // 2*10000*128
  float* out_f2 = out + 2560000;       // 2*10000*128
  float* out_f3 = out + 5120000;       // 2*10000*256
  float* out_coords = out + 10240000;  // 60000
  float* out_masks = out + 10300000;   // 20000
  float* out_sem = out + 10320000;     // 2*10000*20

  dim3 blk(256);
  const int GX = (COLS + 127) / 128;  // 157

  // pack + all EC weight folds in one launch (20000 + 28928 items)
  prep_all<<<dim3(192), blk, 0, stream>>>(coords, feats, X0, ew1, WS1, ew2, WS2, ew3, WS3, ew4,
                                          WS4);

  // EC chain (fp32, proven)
  gemm_kernel<4, 0><<<dim3(GX, 2), blk, 0, stream>>>(WS1, X0, AB, nullptr, nullptr, 0);
  edge_finish<<<dim3(10, 64, 2), blk, 0, stream>>>(AB, 64, es1, et1, XC);
  gemm_kernel<64, 0><<<dim3(GX, 2), blk, 0, stream>>>(WS2, XC, AB, nullptr, nullptr, 0);
  edge_finish<<<dim3(10, 64, 2), blk, 0, stream>>>(AB, 64, es2, et2, XC + (size_t)64 * COLS);
  gemm_kernel<64, 0><<<dim3(GX, 4), blk, 0, stream>>>(WS3, XC + (size_t)64 * COLS, AB, nullptr,
                                                      nullptr, 0);
  edge_finish<<<dim3(10, 128, 2), blk, 0, stream>>>(AB, 128, es3, et3, XC + (size_t)128 * COLS);
  gemm_kernel<128, 0><<<dim3(GX, 4), blk, 0, stream>>>(WS4, XC + (size_t)128 * COLS, AB, nullptr,
                                                       nullptr, 0);
  edge_finish<<<dim3(10, 128, 2), blk, 0, stream>>>(AB, 128, es4, et4, XC + (size_t)256 * COLS);

  // weight prep for MFMA path
  split_w5<<<dim3(768), blk, 0, stream>>>(w5, Wc5);
  sem_prep<<<dim3(40), blk, 0, stream>>>(sem_w, sem_b, fw3, fs3, ft3, SWp, Bp);
  split_wf<<<dim3(1280), blk, 0, stream>>>(fw1, fw2, fw3, SWp, fs1, ft1, fs2, ft2, fs3, ft3, Bp,
                                           WcF, sF, tF);

  // activations: XC -> point-major bf16 hi/lo
  xpose_split<<<dim3(313, 12), blk, 0, stream>>>(XC, XCt);

  // conv5: [512][1152] @ XCt -> Y5t (leaky, split bf16); 1-D swizzled grid, MR=4
  mgemm<1152, 384, 768, 0, 4><<<dim3(GX * 4), blk, 0, stream>>>(Wc5, XCt, nullptr, nullptr,
                                                                nullptr, nullptr, Y5t, s5, t5);

  // fused f1|f2|f3|sem: [640][1536] @ Y5t -> d_out; 1-D swizzled grid, MR=5
  mgemm<1536, 512, 1024, 1, 5><<<dim3(GX * 5), blk, 0, stream>>>(WcF, Y5t, out_f1, out_f2, out_f3,
                                                                 out_sem, nullptr, sF, tF);

  misc_kernel<<<dim3(236), blk, 0, stream>>>(coords, out_coords, out_masks);
}

// Round 11
// 369.792 us; speedup vs baseline: 1.7212x; 1.0352x over previous
//
#include <hip/hip_runtime.h>

#define N_PTS 10000
#define NBATCH 2
#define COLS (N_PTS * NBATCH)

typedef __attribute__((ext_vector_type(8))) short bf16x8;
typedef __attribute__((ext_vector_type(4))) float f32x4;

static __device__ __forceinline__ float leaky(float v) { return v > 0.f ? v : 0.2f * v; }

static __device__ __forceinline__ unsigned short f2b(float x) {
  unsigned int u = __float_as_uint(x);
  unsigned int r = (u + 0x7fffu + ((u >> 16) & 1u)) >> 16;
  return (unsigned short)r;
}
static __device__ __forceinline__ float b2f(unsigned short h) {
  return __uint_as_float((unsigned int)h << 16);
}

// ---------------- fused prep: pack X0 + all 4 EC weight folds ----------------
static __device__ __forceinline__ void prep_one(const float* __restrict__ ew,
                                                float* __restrict__ WS, int O, int C, int i) {
  int o = i / C, c = i - o * C;
  float wa = ew[(size_t)o * 2 * C + c];
  float wb = ew[(size_t)o * 2 * C + C + c];
  WS[(size_t)o * C + c] = wa + wb;
  WS[(size_t)(O + o) * C + c] = wa;
}

__global__ void prep_all(const float* __restrict__ coords, const float* __restrict__ feats,
                         float* __restrict__ X0, const float* __restrict__ ew1,
                         float* __restrict__ WS1, const float* __restrict__ ew2,
                         float* __restrict__ WS2, const float* __restrict__ ew3,
                         float* __restrict__ WS3, const float* __restrict__ ew4,
                         float* __restrict__ WS4) {
  int i = blockIdx.x * 256 + threadIdx.x;
  if (i < COLS) {
    const float* cp = coords + (size_t)i * 3;
    X0[0 * COLS + i] = cp[0];
    X0[1 * COLS + i] = cp[1];
    X0[2 * COLS + i] = cp[2];
    X0[3 * COLS + i] = feats[(size_t)i * 4 + 3];
    return;
  }
  i -= COLS;
  if (i < 256) { prep_one(ew1, WS1, 64, 4, i); return; }
  i -= 256;
  if (i < 4096) { prep_one(ew2, WS2, 64, 64, i); return; }
  i -= 4096;
  if (i < 8192) { prep_one(ew3, WS3, 128, 64, i); return; }
  i -= 8192;
  if (i < 16384) { prep_one(ew4, WS4, 128, 128, i); return; }
}

// ------- fp32 GEMM (EC layers): Out[M][COLS] = W[M][K] @ X[K][COLS], 64x64 tiles -------
// Smaller tiles double the grid (626-1252 blocks) for latency hiding at low M.
template <int K>
__global__ __launch_bounds__(256) void gemm_kernel(const float* __restrict__ W,
                                                   const float* __restrict__ X,
                                                   float* __restrict__ Out) {
  __shared__ float Ws[32][68];
  __shared__ float Xs[32][68];
  const int tid = threadIdx.x;
  const int col0 = blockIdx.x * 64;
  const int row0 = blockIdx.y * 64;
  const int tx = tid & 15, ty = tid >> 4;
  float acc[4][4];
#pragma unroll
  for (int i = 0; i < 4; i++)
#pragma unroll
    for (int j = 0; j < 4; j++) acc[i][j] = 0.f;

  const bool colok = (col0 + tx * 4) < COLS;

  for (int k0 = 0; k0 < K; k0 += 32) {
    {  // W tile: 64 rows x 32 k, transposed to Ws[k][m]
      int m = tid >> 2;
      int kq = (tid & 3) * 8;
      if ((K & 31) == 0) {
        const float* wp = W + (size_t)(row0 + m) * K + k0 + kq;
        float4 w0 = *(const float4*)wp;
        float4 w1 = *(const float4*)(wp + 4);
        Ws[kq + 0][m] = w0.x; Ws[kq + 1][m] = w0.y; Ws[kq + 2][m] = w0.z; Ws[kq + 3][m] = w0.w;
        Ws[kq + 4][m] = w1.x; Ws[kq + 5][m] = w1.y; Ws[kq + 6][m] = w1.z; Ws[kq + 7][m] = w1.w;
      } else {  // K=4 path, guarded scalar
#pragma unroll
        for (int j = 0; j < 8; j++) {
          int k = kq + j;
          Ws[k][m] = (k0 + k < K) ? W[(size_t)(row0 + m) * K + k0 + k] : 0.f;
        }
      }
    }
// X tile: 32 k x 64 cols
#pragma unroll
    for (int p = 0; p < 2; p++) {
      int idx = tid + p * 256;
      int k = idx >> 4;
      int n4 = (idx & 15) << 2;
      int col = col0 + n4;
      float4 v = make_float4(0.f, 0.f, 0.f, 0.f);
      if (k0 + k < K && col < COLS) v = *(const float4*)(X + (size_t)(k0 + k) * COLS + col);
      *(float4*)&Xs[k][n4] = v;
    }
    __syncthreads();
#pragma unroll
    for (int k = 0; k < 32; k++) {
      float a[4], b[4];
      *(float4*)&a[0] = *(const float4*)&Ws[k][ty * 4];
      *(float4*)&b[0] = *(const float4*)&Xs[k][tx * 4];
#pragma unroll
      for (int i = 0; i < 4; i++)
#pragma unroll
        for (int j = 0; j < 4; j++) acc[i][j] = fmaf(a[i], b[j], acc[i][j]);
    }
    __syncthreads();
  }

  if (colok) {
#pragma unroll
    for (int i = 0; i < 4; i++) {
      int row = row0 + ty * 4 + i;
      float4 v = make_float4(acc[i][0], acc[i][1], acc[i][2], acc[i][3]);
      *(float4*)(Out + (size_t)row * COLS + col0 + tx * 4) = v;
    }
  }
}

// ---------------- edge finish: out = leaky((A - slidemin20(Bt, circular)) * s + t) --------
__global__ __launch_bounds__(256) void edge_finish(const float* __restrict__ AB, int O,
                                                   const float* __restrict__ s,
                                                   const float* __restrict__ t,
                                                   float* __restrict__ Xout) {
  __shared__ float sh[1024 + 20];
  int o = blockIdx.y;
  int b = blockIdx.z;
  int n0 = blockIdx.x * 1024;
  int nb = min(1024, N_PTS - n0);
  const float* Bt = AB + (size_t)(O + o) * COLS + (size_t)b * N_PTS;
  int base = N_PTS - n0 - nb + 1;
  int L = nb + 19;
  for (int i = threadIdx.x; i < L; i += 256) {
    int p = base + i;
    if (p >= N_PTS) p -= N_PTS;
    sh[i] = Bt[p];
  }
  __syncthreads();
  const float* Arow = AB + (size_t)o * COLS + (size_t)b * N_PTS;
  float ss = s[o], tt = t[o];
  for (int d = threadIdx.x; d < nb; d += 256) {
    int w = nb - 1 - d;
    float mn = sh[w];
#pragma unroll
    for (int k = 1; k < 20; k++) mn = fminf(mn, sh[w + k]);
    float v = (Arow[n0 + d] - mn) * ss + tt;
    Xout[(size_t)o * COLS + (size_t)b * N_PTS + n0 + d] = leaky(v);
  }
}

// ---------------- fold sem head through Y5: SWp[20][512], biasp[20] ----------------
__global__ void sem_prep(const float* __restrict__ sem_w, const float* __restrict__ sem_b,
                         const float* __restrict__ fw3, const float* __restrict__ fs3,
                         const float* __restrict__ ft3, float* __restrict__ SWp,
                         float* __restrict__ biasp) {
  int i = blockIdx.x * blockDim.x + threadIdx.x;
  if (i < 20 * 512) {
    int cls = i / 512, k = i - cls * 512;
    float acc = 0.f;
    for (int c = 0; c < 256; c++) acc += sem_w[cls * 256 + c] * fs3[c] * fw3[(size_t)c * 512 + k];
    SWp[i] = acc;
  }
  if (i < 20) {
    float acc = sem_b[i];
    for (int c = 0; c < 256; c++) acc += sem_w[i * 256 + c] * ft3[c];
    biasp[i] = acc;
  }
}

// ------------- split conv5 weights: Wc[512][1152] = [hi | hi | lo] of w5[512][384] -------
__global__ void split_w5(const float* __restrict__ w5, unsigned short* __restrict__ Wc) {
  int i = blockIdx.x * 256 + threadIdx.x;
  if (i >= 512 * 384) return;
  int m = i / 384, k = i - m * 384;
  float w = w5[i];
  unsigned short hi = f2b(w);
  unsigned short lo = f2b(w - b2f(hi));
  unsigned short* row = Wc + (size_t)m * 1152;
  row[k] = hi;
  row[384 + k] = hi;
  row[768 + k] = lo;
}

// ------------- split fused-f weights: Wc[640][1536]; rows: fw1|fw2|fw3|SWp|zeros ---------
__global__ void split_wf(const float* __restrict__ fw1, const float* __restrict__ fw2,
                         const float* __restrict__ fw3, const float* __restrict__ SWp,
                         const float* __restrict__ fs1, const float* __restrict__ ft1,
                         const float* __restrict__ fs2, const float* __restrict__ ft2,
                         const float* __restrict__ fs3, const float* __restrict__ ft3,
                         const float* __restrict__ Bp, unsigned short* __restrict__ Wc,
                         float* __restrict__ sF, float* __restrict__ tF) {
  int i = blockIdx.x * 256 + threadIdx.x;
  if (i >= 640 * 512) return;
  int m = i >> 9, k = i & 511;
  float w = 0.f, sv = 0.f, tv = 0.f;
  if (m < 128) {
    w = fw1[(size_t)m * 512 + k]; sv = fs1[m]; tv = ft1[m];
  } else if (m < 256) {
    w = fw2[(size_t)(m - 128) * 512 + k]; sv = fs2[m - 128]; tv = ft2[m - 128];
  } else if (m < 512) {
    w = fw3[(size_t)(m - 256) * 512 + k]; sv = fs3[m - 256]; tv = ft3[m - 256];
  } else if (m < 532) {
    w = SWp[(size_t)(m - 512) * 512 + k]; sv = 1.f; tv = Bp[m - 512];
  }
  unsigned short hi = f2b(w);
  unsigned short lo = f2b(w - b2f(hi));
  unsigned short* row = Wc + (size_t)m * 1536;
  row[k] = hi;
  row[512 + k] = hi;
  row[1024 + k] = lo;
  if (k == 0) { sF[m] = sv; tF[m] = tv; }
}

// ------------- transpose+split XC[384][COLS] fp32 -> XCt[n][768] bf16 (hi|lo) ------------
__global__ __launch_bounds__(256) void xpose_split(const float* __restrict__ XC,
                                                   unsigned short* __restrict__ XCt) {
  __shared__ float tile[32][65];
  int n0 = blockIdx.x * 64;
  int c0 = blockIdx.y * 32;
#pragma unroll
  for (int i = 0; i < 8; i++) {
    int e = threadIdx.x + i * 256;
    int c = e >> 6, n = e & 63;
    float v = 0.f;
    if (n0 + n < COLS) v = XC[(size_t)(c0 + c) * COLS + n0 + n];
    tile[c][n] = v;
  }
  __syncthreads();
#pragma unroll
  for (int i = 0; i < 2; i++) {
    int e = threadIdx.x + i * 256;
    int n = e >> 3, cq = (e & 7) * 4;
    if (n0 + n >= COLS) continue;
    unsigned short h[4], l[4];
#pragma unroll
    for (int j = 0; j < 4; j++) {
      float v = tile[cq + j][n];
      h[j] = f2b(v);
      l[j] = f2b(v - b2f(h[j]));
    }
    unsigned short* op = XCt + (size_t)(n0 + n) * 768 + c0 + cq;
    *(ushort4*)op = make_ushort4(h[0], h[1], h[2], h[3]);
    *(ushort4*)(op + 384) = make_ushort4(l[0], l[1], l[2], l[3]);
  }
}

// ---------------- MFMA GEMM: 64-row x 128-col tiles + T1 XCD col-tile swizzle ----------
// 4 waves, each 64rows x 32cols (a-frags shared). Doubled grid (1256/1570 blocks)
// attacks the measured grid-limited occupancy (r10: Occ 20%, MfmaUtil 18%).
// Bijective chunked XCD remap (m204), row-tile fastest => column slab L2-resident.
// Chunk swizzle j -> j ^ ((row>>1)&3) on BOTH global source and ds_read (G-21).
// MODE 0: conv5 -> Y5t[n][1024] bf16 hi|lo, val=leaky(v*s+t).
// MODE 1: fused f1/f2/f3/sem fp32 stores, val=v*s+t, rows 0/128/256/512..532.
template <int KP, int KX, int XSTR, int MODE, int MR>
__global__ __launch_bounds__(256) void mgemm(
    const unsigned short* __restrict__ Wc, const unsigned short* __restrict__ Xt,
    float* __restrict__ O0, float* __restrict__ O1, float* __restrict__ O2,
    float* __restrict__ O3, unsigned short* __restrict__ Yt, const float* __restrict__ s,
    const float* __restrict__ t) {
  __shared__ unsigned short Al[64 * 32];
  __shared__ unsigned short Bl[128 * 32];
  const int tid = threadIdx.x;
  const int wid = tid >> 6, lane = tid & 63;
  const int B = gridDim.x;
  const int q = B >> 3, r = B & 7;
  const int xcd = blockIdx.x & 7, jj0 = blockIdx.x >> 3;
  const int tIdx = xcd * q + min(xcd, r) + jj0;
  const int col0 = (tIdx / MR) * 128;
  const int row0 = (tIdx - (tIdx / MR) * MR) * 64;
  f32x4 acc[4][2];
  f32x4 z = {0.f, 0.f, 0.f, 0.f};
#pragma unroll
  for (int i = 0; i < 4; i++)
#pragma unroll
    for (int j = 0; j < 2; j++) acc[i][j] = z;

  for (int k0 = 0; k0 < KP; k0 += 32) {
    int xoff = (k0 < 2 * KX) ? k0 : k0 - 2 * KX;
#pragma unroll
    for (int p = 0; p < 3; p++) {
      int idx = tid + p * 256;  // 0..255: A chunks; 256..767: B chunks (wave-uniform split)
      if (idx < 256) {
        int rr = idx >> 2, jc = idx & 3;
        int js = jc ^ ((rr >> 1) & 3);
        __builtin_amdgcn_global_load_lds(
            (const __attribute__((address_space(1))) unsigned int*)(Wc + (size_t)(row0 + rr) * KP +
                                                                    k0 + js * 8),
            (__attribute__((address_space(3))) unsigned int*)(Al + idx * 8), 16, 0, 0);
      } else {
        int bidx = idx - 256;
        int rr = bidx >> 2, jc = bidx & 3;
        int js = jc ^ ((rr >> 1) & 3);
        __builtin_amdgcn_global_load_lds(
            (const __attribute__((address_space(1))) unsigned int*)(Xt + (size_t)(col0 + rr) * XSTR +
                                                                    xoff + js * 8),
            (__attribute__((address_space(3))) unsigned int*)(Bl + bidx * 8), 16, 0, 0);
      }
    }
    __syncthreads();
    bf16x8 a[4], b[2];
#pragma unroll
    for (int f = 0; f < 4; f++) {
      int m = f * 16 + (lane & 15);
      int ja = (lane >> 4) ^ ((m >> 1) & 3);
      a[f] = *(const bf16x8*)(Al + m * 32 + ja * 8);
    }
#pragma unroll
    for (int j = 0; j < 2; j++) {
      int n = wid * 32 + j * 16 + (lane & 15);
      int jb = (lane >> 4) ^ ((n >> 1) & 3);
      b[j] = *(const bf16x8*)(Bl + n * 32 + jb * 8);
    }
#pragma unroll
    for (int i = 0; i < 4; i++)
#pragma unroll
      for (int j = 0; j < 2; j++)
        acc[i][j] = __builtin_amdgcn_mfma_f32_16x16x32_bf16(a[i], b[j], acc[i][j], 0, 0, 0);
    __syncthreads();
  }

  // epilogue: lane holds D[4*(lane>>4)+r][lane&15] per 16x16 frag
#pragma unroll
  for (int j = 0; j < 2; j++) {
    int n = col0 + wid * 32 + j * 16 + (lane & 15);
    if (n >= COLS) continue;
#pragma unroll
    for (int i = 0; i < 4; i++) {
      int mb = row0 + i * 16 + 4 * (lane >> 4);
      if (MODE == 0) {
        unsigned short h[4], l[4];
#pragma unroll
        for (int rr = 0; rr < 4; rr++) {
          float v = acc[i][j][rr] * s[mb + rr] + t[mb + rr];
          v = leaky(v);
          h[rr] = f2b(v);
          l[rr] = f2b(v - b2f(h[rr]));
        }
        unsigned short* yp = Yt + (size_t)n * 1024 + mb;
        *(ushort4*)yp = make_ushort4(h[0], h[1], h[2], h[3]);
        *(ushort4*)(yp + 512) = make_ushort4(l[0], l[1], l[2], l[3]);
      } else {
        float4 v;
        v.x = acc[i][j][0] * s[mb + 0] + t[mb + 0];
        v.y = acc[i][j][1] * s[mb + 1] + t[mb + 1];
        v.z = acc[i][j][2] * s[mb + 2] + t[mb + 2];
        v.w = acc[i][j][3] * s[mb + 3] + t[mb + 3];
        float* p;
        if (mb < 128)
          p = O0 + (size_t)n * 128 + mb;
        else if (mb < 256)
          p = O1 + (size_t)n * 128 + (mb - 128);
        else if (mb < 512)
          p = O2 + (size_t)n * 256 + (mb - 256);
        else if (mb < 532)
          p = O3 + (size_t)n * 20 + (mb - 512);
        else
          continue;
        *(float4*)p = v;
      }
    }
  }
}

// ---------------- coords passthrough + zero masks ----------------
__global__ void misc_kernel(const float* __restrict__ coords, float* __restrict__ out_coords,
                            float* __restrict__ out_masks) {
  int i = blockIdx.x * blockDim.x + threadIdx.x;
  if (i < NBATCH * N_PTS * 3) out_coords[i] = coords[i];
  if (i < NBATCH * N_PTS) out_masks[i] = 0.f;
}

extern "C" void kernel_launch(void* const* d_in, const int* in_sizes, int n_in, void* d_out,
                              int out_size, void* d_ws, size_t ws_size, hipStream_t stream) {
  const float* coords = (const float*)d_in[0];
  const float* feats = (const float*)d_in[1];
  const float* ew1 = (const float*)d_in[2];
  const float* es1 = (const float*)d_in[3];
  const float* et1 = (const float*)d_in[4];
  const float* ew2 = (const float*)d_in[5];
  const float* es2 = (const float*)d_in[6];
  const float* et2 = (const float*)d_in[7];
  const float* ew3 = (const float*)d_in[8];
  const float* es3 = (const float*)d_in[9];
  const float* et3 = (const float*)d_in[10];
  const float* ew4 = (const float*)d_in[11];
  const float* es4 = (const float*)d_in[12];
  const float* et4 = (const float*)d_in[13];
  const float* w5 = (const float*)d_in[14];
  const float* s5 = (const float*)d_in[15];
  const float* t5 = (const float*)d_in[16];
  const float* fw1 = (const float*)d_in[17];
  const float* fs1 = (const float*)d_in[18];
  const float* ft1 = (const float*)d_in[19];
  const float* fw2 = (const float*)d_in[20];
  const float* fs2 = (const float*)d_in[21];
  const float* ft2 = (const float*)d_in[22];
  const float* fw3 = (const float*)d_in[23];
  const float* fs3 = (const float*)d_in[24];
  const float* ft3 = (const float*)d_in[25];
  const float* sem_w = (const float*)d_in[26];
  const float* sem_b = (const float*)d_in[27];
  float* out = (float*)d_out;
  float* ws = (float*)d_ws;

  // workspace layout (float offsets; total 21,452,736 f = 85.8 MB)
  float* X0 = ws;                                    // 80000
  float* WS1 = ws + 80000;                           // 512
  float* WS2 = ws + 80512;                           // 8192
  float* WS3 = ws + 88704;                           // 16384
  float* WS4 = ws + 105088;                          // 32768
  float* sF = ws + 137856;                           // 640
  float* tF = ws + 138496;                           // 640
  float* SWp = ws + 139136;                          // 10240
  float* Bp = ws + 149376;                           // 64
  unsigned short* Wc5 = (unsigned short*)(ws + 149440);   // 512*1152 ush
  unsigned short* WcF = (unsigned short*)(ws + 444352);   // 640*1536 ush
  unsigned short* XCt = (unsigned short*)(ws + 935872);   // 20096*768 ush
  float* AB = ws + 8652736;                          // 256*20000 f
  float* XC = ws + 13772736;                         // 384*20000 f
  // Y5t aliases AB..XC region (both dead after xpose_split): 20096*1024 ush
  unsigned short* Y5t = (unsigned short*)(ws + 8652736);

  // d_out layout (floats)
  float* out_f1 = out;                 // 2*10000*128
  float* out_f2 = out + 2560000;       // 2*10000*128
  float* out_f3 = out + 5120000;       // 2*10000*256
  float* out_coords = out + 10240000;  // 60000
  float* out_masks = out + 10300000;   // 20000
  float* out_sem = out + 10320000;     // 2*10000*20

  dim3 blk(256);
  const int GX = (COLS + 127) / 128;    // 157 (mgemm col tiles)
  const int GX64 = (COLS + 63) / 64;    // 313 (fp32 gemm col tiles)

  // pack + all EC weight folds in one launch (20000 + 28928 items)
  prep_all<<<dim3(192), blk, 0, stream>>>(coords, feats, X0, ew1, WS1, ew2, WS2, ew3, WS3, ew4,
                                          WS4);

  // EC chain (fp32, 64x64 tiles)
  gemm_kernel<4><<<dim3(GX64, 2), blk, 0, stream>>>(WS1, X0, AB);
  edge_finish<<<dim3(10, 64, 2), blk, 0, stream>>>(AB, 64, es1, et1, XC);
  gemm_kernel<64><<<dim3(GX64, 2), blk, 0, stream>>>(WS2, XC, AB);
  edge_finish<<<dim3(10, 64, 2), blk, 0, stream>>>(AB, 64, es2, et2, XC + (size_t)64 * COLS);
  gemm_kernel<64><<<dim3(GX64, 4), blk, 0, stream>>>(WS3, XC + (size_t)64 * COLS, AB);
  edge_finish<<<dim3(10, 128, 2), blk, 0, stream>>>(AB, 128, es3, et3, XC + (size_t)128 * COLS);
  gemm_kernel<128><<<dim3(GX64, 4), blk, 0, stream>>>(WS4, XC + (size_t)128 * COLS, AB);
  edge_finish<<<dim3(10, 128, 2), blk, 0, stream>>>(AB, 128, es4, et4, XC + (size_t)256 * COLS);

  // weight prep for MFMA path
  split_w5<<<dim3(768), blk, 0, stream>>>(w5, Wc5);
  sem_prep<<<dim3(40), blk, 0, stream>>>(sem_w, sem_b, fw3, fs3, ft3, SWp, Bp);
  split_wf<<<dim3(1280), blk, 0, stream>>>(fw1, fw2, fw3, SWp, fs1, ft1, fs2, ft2, fs3, ft3, Bp,
                                           WcF, sF, tF);

  // activations: XC -> point-major bf16 hi/lo
  xpose_split<<<dim3(313, 12), blk, 0, stream>>>(XC, XCt);

  // conv5: [512][1152] @ XCt -> Y5t (leaky, split bf16); 64-row tiles, MR=8
  mgemm<1152, 384, 768, 0, 8><<<dim3(GX * 8), blk, 0, stream>>>(Wc5, XCt, nullptr, nullptr,
                                                                nullptr, nullptr, Y5t, s5, t5);

  // fused f1|f2|f3|sem: [640][1536] @ Y5t -> d_out; 64-row tiles, MR=10
  mgemm<1536, 512, 1024, 1, 10><<<dim3(GX * 10), blk, 0, stream>>>(WcF, Y5t, out_f1, out_f2,
                                                                   out_f3, out_sem, nullptr, sF,
                                                                   tF);

  misc_kernel<<<dim3(236), blk, 0, stream>>>(coords, out_coords, out_masks);
}